// Round 7
// baseline (317.116 us; speedup 1.0000x reference)
//
#include <hip/hip_runtime.h>
#include <hip/hip_bf16.h>
#include <stdint.h>

typedef __attribute__((ext_vector_type(4))) float f32x4;
typedef __attribute__((ext_vector_type(8))) __bf16 bf16x8;
typedef __attribute__((ext_vector_type(8))) unsigned short u16x8;

__device__ __forceinline__ unsigned short f2bf(float f){
  uint32_t u = __builtin_bit_cast(uint32_t, f);
  u += 0x7FFFu + ((u >> 16) & 1u);
  return (unsigned short)(u >> 16);
}
__device__ __forceinline__ float bf2f(unsigned short h){
  return __builtin_bit_cast(float, ((uint32_t)h) << 16);
}
__device__ __forceinline__ float fast_exp2(float x){
#if __has_builtin(__builtin_amdgcn_exp2f)
  return __builtin_amdgcn_exp2f(x);
#else
  return exp2f(x);
#endif
}
__device__ __forceinline__ void gl_lds16(const unsigned short* g, unsigned short* l){
  __builtin_amdgcn_global_load_lds(
      (const __attribute__((address_space(1))) uint32_t*)g,
      (__attribute__((address_space(3))) uint32_t*)l, 16, 0, 0);
}

// ---------------- fp32 -> bf16 convert (all 4 weights, one launch) ----------------
__global__ __launch_bounds__(256) void conv4(const float* __restrict__ a, const float* __restrict__ b,
                                             const float* __restrict__ c, const float* __restrict__ d,
                                             unsigned short* __restrict__ oa, unsigned short* __restrict__ ob,
                                             unsigned short* __restrict__ oc, unsigned short* __restrict__ od){
  const int bid = blockIdx.x;            // 512 blocks; 128 per weight
  const int sel = bid >> 7;
  const float* in = sel == 0 ? a : sel == 1 ? b : sel == 2 ? c : d;
  unsigned short* out = sel == 0 ? oa : sel == 1 ? ob : sel == 2 ? oc : od;
  const int i = ((bid & 127) * 256 + threadIdx.x) * 8;
  float4 v0 = *(const float4*)&in[i];
  float4 v1 = *(const float4*)&in[i + 4];
  u16x8 o;
  o[0]=f2bf(v0.x); o[1]=f2bf(v0.y); o[2]=f2bf(v0.z); o[3]=f2bf(v0.w);
  o[4]=f2bf(v1.x); o[5]=f2bf(v1.y); o[6]=f2bf(v1.z); o[7]=f2bf(v1.w);
  *(u16x8*)&out[i] = o;
}

// ---------------- GroupNorm stats, 2-stage ----------------
__global__ __launch_bounds__(256) void gn_stats1(const float* __restrict__ x,
                                                 float* __restrict__ part){
  const int bid = blockIdx.x;            // 1024 segments of 8192 floats
  const float* p = x + (size_t)bid * 8192;
  float s = 0.f, ss = 0.f;
  for (int i = threadIdx.x; i < 2048; i += 256) {
    float4 v = *(const float4*)(p + (size_t)i * 4);
    s  += v.x + v.y + v.z + v.w;
    ss += v.x*v.x + v.y*v.y + v.z*v.z + v.w*v.w;
  }
  for (int off = 32; off; off >>= 1) { s += __shfl_down(s, off); ss += __shfl_down(ss, off); }
  __shared__ float red[8];
  int w = threadIdx.x >> 6;
  if ((threadIdx.x & 63) == 0) { red[w] = s; red[w + 4] = ss; }
  __syncthreads();
  if (threadIdx.x == 0) {
    part[bid * 2]     = red[0] + red[1] + red[2] + red[3];
    part[bid * 2 + 1] = red[4] + red[5] + red[6] + red[7];
  }
}
__global__ __launch_bounds__(128) void gn_stats2(const float* __restrict__ part,
                                                 float* __restrict__ stats){
  const int g = threadIdx.x;             // 128 groups
  float s = 0.f, ss = 0.f;
#pragma unroll
  for (int i = 0; i < 8; i++) { s += part[(g * 8 + i) * 2]; ss += part[(g * 8 + i) * 2 + 1]; }
  float mean = s * (1.f / 65536.f);
  float var  = ss * (1.f / 65536.f) - mean * mean;
  stats[g * 2]     = mean;
  stats[g * 2 + 1] = rsqrtf(var + 1e-6f);
}

// ---------------- GN apply + transpose ----------------
__global__ __launch_bounds__(256) void gn_apply(const float* __restrict__ x,
                                                const float* __restrict__ stats,
                                                const float* __restrict__ gamma,
                                                const float* __restrict__ beta,
                                                unsigned short* __restrict__ hn_t){
  __shared__ float tile[32][33];
  int b  = blockIdx.z;
  int c0 = blockIdx.y * 32;
  int p0 = blockIdx.x * 32;
  int tx = threadIdx.x & 31, ty = threadIdx.x >> 5;
  const float* xb = x + (size_t)b * 512 * 4096;
#pragma unroll
  for (int i = 0; i < 32; i += 8)
    tile[ty + i][tx] = xb[(size_t)(c0 + ty + i) * 4096 + p0 + tx];
  __syncthreads();
  unsigned short* hb = hn_t + (size_t)b * 4096 * 512;
  int c = c0 + tx;
  float mean = stats[(b * 32 + (c >> 4)) * 2];
  float rstd = stats[(b * 32 + (c >> 4)) * 2 + 1];
  float ga = gamma[c], be = beta[c];
#pragma unroll
  for (int i = 0; i < 32; i += 8) {
    float v = tile[tx][ty + i];
    hb[(size_t)(p0 + ty + i) * 512 + c] = f2bf((v - mean) * rstd * ga + be);
  }
}

// =====================================================================
// gemm8: deep-pipelined 256x256 GEMM, BK=32, NBUF=4, 8 waves (2M x 4N).
// Per K-tile: 4 phases (gray order 00,01,11,10), each:
//   [vmcnt(8); ds_read quadrant; stage 1 unit of tile j+3; barrier;
//    lgkmcnt(0); setprio(1); 8 MFMA; setprio(0)]
// Reads issue pre-barrier -> LDS drain overlaps previous phase's MFMA drain.
// Stage order (A0,B0,A1,B1) one call/phase; in-order vmcnt(8) proves all
// stages >= 2 tiles old are complete before each guarded read (tail: vm4/vm0).
// MODE 3: scores (mask*exp2 + row partial sums); MODE 6: PV split-K partial.
// =====================================================================
template<int MODE>
__global__ __launch_bounds__(512, 2)
void gemm8(const unsigned short* __restrict__ A, const unsigned short* __restrict__ B,
           unsigned short* __restrict__ C, const float* __restrict__ auxA,
           float* __restrict__ auxW,
           int M, int N, int K, int ldA, int ldB, float scale,
           size_t sA, size_t sB, size_t sC, int gx, int gy)
{
  __shared__ __align__(16) unsigned short As[4 * 8192];   // 64 KB
  __shared__ __align__(16) unsigned short Bs[4 * 8192];   // 64 KB

  const int lin = blockIdx.x;
  const int nwg = gridDim.x;
  const int wg = ((lin & 7) * (nwg >> 3)) + (lin >> 3);
  const int bx = wg % gx;
  const int t2 = wg / gx;
  const int by = t2 % gy;
  const int bz = t2 / gy;

  const unsigned short* Ab;
  const unsigned short* Bb;
  if constexpr (MODE == 6) {
    const int bb = bz & 3, ks = bz >> 2;
    Ab = A + (size_t)bb * sA + ks * 2048;
    Bb = B + (size_t)bb * sB + ks * 2048;
  } else {
    Ab = A + (size_t)bz * sA;
    Bb = B + (size_t)bz * sB;
  }
  const int brow = bx * 256;
  const int bcol = by * 256;
  const int t = threadIdx.x;
  const int lane = t & 63;
  const int wid = t >> 6;
  const int wr = wid >> 2;        // 0..1
  const int wc = wid & 3;         // 0..3
  const int la = lane & 15;
  const int lk = lane >> 4;       // 0..3

  const f32x4 zero = {0.f, 0.f, 0.f, 0.f};
  f32x4 acc[8][4];
#pragma unroll
  for (int m = 0; m < 8; m++)
#pragma unroll
    for (int n = 0; n < 4; n++) acc[m][n] = zero;

  // ---- stage addressing (pre-swizzled global source, linear LDS dest) ----
  const int lr  = t >> 2;                       // 0..127
  const int sst = t & 3;
  const int rab = (lr < 64) ? lr : (lr + 64);   // A unit row base (mh*64 added later)
  const int rbb = ((lr >> 5) << 6) + (lr & 31); // B unit row base (nh*32 added later)
  const int gA  = sst ^ ((rab >> 1) & 3);       // mh-invariant
  const int gB  = sst ^ ((rbb >> 1) & 3);       // nh-invariant

  auto stageA = [&](int kt, int buf, int mh) {
    const int r = mh * 64 + rab;
    gl_lds16(Ab + (size_t)(brow + r) * ldA + kt * 32 + gA * 8,
             &As[buf * 8192 + r * 32 + sst * 8]);
  };
  auto stageB = [&](int kt, int buf, int nh) {
    const int r = nh * 32 + rbb;
    gl_lds16(Bb + (size_t)(bcol + r) * ldB + kt * 32 + gB * 8,
             &Bs[buf * 8192 + r * 32 + sst * 8]);
  };

  // ---- fragment read addressing ----
  const int arw = wr * 128 + la;
  const int brw = wc * 64 + la;
  const int axA = (arw >> 1) & 3;               // invariant under +16/+64
  const int axB = (brw >> 1) & 3;               // invariant under +16/+32
  auto LDA = [&](int buf, int mh, int i) -> bf16x8 {
    return __builtin_bit_cast(bf16x8, *(const u16x8*)
      &As[buf * 8192 + (arw + mh * 64 + i * 16) * 32 + ((lk ^ axA) * 8)]);
  };
  auto LDB = [&](int buf, int nh, int n2) -> bf16x8 {
    return __builtin_bit_cast(bf16x8, *(const u16x8*)
      &Bs[buf * 8192 + (brw + nh * 32 + n2 * 16) * 32 + ((lk ^ axB) * 8)]);
  };

  bf16x8 aq[4], bqA[2], bqB[2];

#define SB0 __builtin_amdgcn_sched_barrier(0)
#define VM8 asm volatile("s_waitcnt vmcnt(8)" ::: "memory")
#define VM4 asm volatile("s_waitcnt vmcnt(4)" ::: "memory")
#define VMZ asm volatile("s_waitcnt vmcnt(0)" ::: "memory")
#define VMN ((void)0)
#define BARR do { SB0; __builtin_amdgcn_s_barrier(); SB0; \
  asm volatile("s_waitcnt lgkmcnt(0)" ::: "memory"); SB0; } while (0)
#define MFMAQ(mh, nh, BQ) do { \
  __builtin_amdgcn_s_setprio(1); \
  _Pragma("unroll") \
  for (int i = 0; i < 4; ++i) { \
    _Pragma("unroll") \
    for (int n2 = 0; n2 < 2; ++n2) \
      acc[(mh)*4+i][(nh)*2+n2] = __builtin_amdgcn_mfma_f32_16x16x32_bf16( \
          aq[i], BQ[n2], acc[(mh)*4+i][(nh)*2+n2], 0, 0, 0); \
  } \
  __builtin_amdgcn_s_setprio(0); SB0; } while (0)

#define TILE_BODY(VMA, VMB, VMC, VMD, DS, jj, sb, bi) do { \
  VMA; \
  aq[0]=LDA(bi,0,0); aq[1]=LDA(bi,0,1); aq[2]=LDA(bi,0,2); aq[3]=LDA(bi,0,3); \
  bqA[0]=LDB(bi,0,0); bqA[1]=LDB(bi,0,1); \
  if (DS) stageA(jj, sb, 0); \
  BARR; MFMAQ(0,0,bqA); \
  VMB; \
  bqB[0]=LDB(bi,1,0); bqB[1]=LDB(bi,1,1); \
  if (DS) stageB(jj, sb, 0); \
  BARR; MFMAQ(0,1,bqB); \
  VMC; \
  aq[0]=LDA(bi,1,0); aq[1]=LDA(bi,1,1); aq[2]=LDA(bi,1,2); aq[3]=LDA(bi,1,3); \
  if (DS) stageA(jj, sb, 1); \
  BARR; MFMAQ(1,1,bqB); \
  VMD; \
  bqA[0]=LDB(bi,0,0); bqA[1]=LDB(bi,0,1); \
  if (DS) stageB(jj, sb, 1); \
  BARR; MFMAQ(1,0,bqA); \
} while (0)

  const int nk = K >> 5;   // >= 16 for all uses
  // prologue: stage tiles 0,1,2 (12 calls), ensure tile 0 resident
  stageA(0, 0, 0); stageB(0, 0, 0); stageA(0, 0, 1); stageB(0, 0, 1);
  stageA(1, 1, 0); stageB(1, 1, 0); stageA(1, 1, 1); stageB(1, 1, 1);
  stageA(2, 2, 0); stageB(2, 2, 0); stageA(2, 2, 1); stageB(2, 2, 1);
  VM8; SB0;
  __builtin_amdgcn_s_barrier(); SB0;

  for (int j = 0; j < nk - 3; ++j) {
    const int bi = j & 3, sb = (j + 3) & 3;
    TILE_BODY(VM8, VM8, VM8, VM8, true, j + 3, sb, bi);
  }
  { const int bi = (nk - 3) & 3; TILE_BODY(VM8, VM8, VM8, VM8, false, 0, 0, bi); }
  { const int bi = (nk - 2) & 3; TILE_BODY(VM4, VMN, VMN, VMN, false, 0, 0, bi); }
  { const int bi = (nk - 1) & 3; TILE_BODY(VMZ, VMN, VMN, VMN, false, 0, 0, bi); }

#undef TILE_BODY
#undef MFMAQ
#undef BARR
#undef VM8
#undef VM4
#undef VMZ
#undef VMN
#undef SB0

  // epilogue: C/D layout col=lane&15, row=(lane>>4)*4+j
  const int cl = la;
  const int rg = lk * 4;
  const int rowbase = brow + wr * 128;
  const int colbase = bcol + wc * 64;

  if constexpr (MODE == 3) {
    unsigned short* Cb = C + (size_t)bz * sC;
    const float* maskb = auxA + (size_t)bz * 4096;
    float* partb = auxW + ((size_t)bz * 64 + (size_t)(by * 4 + wc)) * M;
    const float sc2 = scale * 1.4426950408889634f;
    f32x4 rs[8];
#pragma unroll
    for (int m = 0; m < 8; m++) rs[m] = zero;
#pragma unroll
    for (int m = 0; m < 8; m++) {
#pragma unroll
      for (int n = 0; n < 4; n++) {
        const int col = colbase + n * 16 + cl;
        const float mk = maskb[col];
#pragma unroll
        for (int j = 0; j < 4; j++) {
          const int row = rowbase + m * 16 + rg + j;
          float v = mk * fast_exp2(acc[m][n][j] * sc2);
          rs[m][j] += v;
          Cb[(size_t)row * N + col] = f2bf(v);
        }
      }
    }
#pragma unroll
    for (int off = 1; off < 16; off <<= 1)
#pragma unroll
      for (int m = 0; m < 8; m++) {
#pragma unroll
        for (int j = 0; j < 4; j++) rs[m][j] += __shfl_xor(rs[m][j], off);
      }
    if (cl == 0) {
#pragma unroll
      for (int m = 0; m < 8; m++) {
        float4 v = make_float4(rs[m][0], rs[m][1], rs[m][2], rs[m][3]);
        *(float4*)&partb[rowbase + m * 16 + rg] = v;
      }
    }
  } else { // MODE 6: raw bf16 partial
    unsigned short* Cb = C + (size_t)bz * sC;
#pragma unroll
    for (int m = 0; m < 8; m++) {
#pragma unroll
      for (int n = 0; n < 4; n++) {
        const int col = colbase + n * 16 + cl;
#pragma unroll
        for (int j = 0; j < 4; j++) {
          const int row = rowbase + m * 16 + rg + j;
          Cb[(size_t)row * N + col] = f2bf(acc[m][n][j]);
        }
      }
    }
  }
}

// ---------------- single-phase 256x128 GEMM (projections, R6 body) ----------------
// MODE 1: +bias[col]->bf16 | 2: +bias[row]->bf16 | 5: acc+resid+bias[col]->fp32 transposed
template<int MODE, int BN>
__device__ __forceinline__ void gemm_body(
    const unsigned short* __restrict__ A, const unsigned short* __restrict__ B,
    unsigned short* __restrict__ C, float* __restrict__ OUTF,
    const float* __restrict__ auxA, const float* __restrict__ auxB,
    float* __restrict__ auxW,
    int M, int N, int K, float scale,
    size_t sA, size_t sB, size_t sC, int gx, int gy)
{
  constexpr int NBUF    = 3;
  constexpr int WAVES_N = 2;
  constexpr int MF      = 4;
  constexpr int NF      = 4;
  constexpr int BCALLS  = BN / 128;
  constexpr int BSTRIDE = BN * 32;

  __shared__ __align__(16) unsigned short As[NBUF * 8192];
  __shared__ __align__(16) unsigned short Bs[NBUF * BSTRIDE];

  const int lin = blockIdx.x;
  const int nwg = gridDim.x;
  const int wg = ((lin & 7) * (nwg >> 3)) + (lin >> 3);
  const int bx = wg % gx;
  const int t2 = wg / gx;
  const int by = t2 % gy;
  const int bz = t2 / gy;

  const unsigned short* Ab = A + (size_t)bz * sA;
  const unsigned short* Bb = B + (size_t)bz * sB;
  const int brow = bx * 256;
  const int bcol = by * BN;
  const int t = threadIdx.x;
  const int lane = t & 63;
  const int wid = t >> 6;
  const int wr = wid / WAVES_N;
  const int wc = wid % WAVES_N;
  const int la = lane & 15;
  const int lk = lane >> 4;
  const int axr = (la >> 1) & 3;

  const f32x4 zero = {0.f, 0.f, 0.f, 0.f};
  f32x4 acc[MF][NF];
#pragma unroll
  for (int m = 0; m < MF; m++)
#pragma unroll
    for (int n = 0; n < NF; n++) acc[m][n] = zero;

  const unsigned short* srcA[2];
  const unsigned short* srcB[BCALLS];
#pragma unroll
  for (int c = 0; c < 2; ++c) {
    const int q = c * 512 + t, r = q >> 2, s = (q & 3) ^ ((r >> 1) & 3);
    srcA[c] = Ab + (size_t)(brow + r) * K + s * 8;
  }
#pragma unroll
  for (int c = 0; c < BCALLS; ++c) {
    const int q = c * 512 + t, r = q >> 2, s = (q & 3) ^ ((r >> 1) & 3);
    srcB[c] = Bb + (size_t)(bcol + r) * K + s * 8;
  }

  auto STAGE = [&](int kt, int buf) {
    const int ko = kt * 32;
#pragma unroll
    for (int c = 0; c < 2; ++c)
      gl_lds16(srcA[c] + ko, &As[buf * 8192 + (c * 512 + t) * 8]);
#pragma unroll
    for (int c = 0; c < BCALLS; ++c)
      gl_lds16(srcB[c] + ko, &Bs[buf * BSTRIDE + (c * 512 + t) * 8]);
  };
  auto LDA = [&](int buf, int m) -> bf16x8 {
    const int ru = wr * (MF * 16) + m * 16 + la;
    const int slot = lk ^ axr;
    return __builtin_bit_cast(bf16x8, *(const u16x8*)&As[buf * 8192 + ru * 32 + slot * 8]);
  };
  auto LDB = [&](int buf, int n) -> bf16x8 {
    const int ru = wc * (NF * 16) + n * 16 + la;
    const int slot = lk ^ axr;
    return __builtin_bit_cast(bf16x8, *(const u16x8*)&Bs[buf * BSTRIDE + ru * 32 + slot * 8]);
  };

  const int nk = K >> 5;
  STAGE(0, 0);
  STAGE(1, 1);
  int bi = 0;
  int bs = 2 % NBUF;
  for (int j = 0; j < nk; ++j) {
    if (j == nk - 1) {
      asm volatile("s_waitcnt vmcnt(0)" ::: "memory");
    } else {
      asm volatile("s_waitcnt vmcnt(3)" ::: "memory");
    }
    __builtin_amdgcn_s_barrier();
    __builtin_amdgcn_sched_barrier(0);
    bf16x8 bq[NF], aq[MF];
#pragma unroll
    for (int n = 0; n < NF; n++) bq[n] = LDB(bi, n);
#pragma unroll
    for (int m = 0; m < MF; m++) aq[m] = LDA(bi, m);
    if (j + 2 < nk) STAGE(j + 2, bs);
    asm volatile("s_waitcnt lgkmcnt(0)" ::: "memory");
    __builtin_amdgcn_sched_barrier(0);
    __builtin_amdgcn_s_setprio(1);
#pragma unroll
    for (int m = 0; m < MF; m++)
#pragma unroll
      for (int n = 0; n < NF; n++)
        acc[m][n] = __builtin_amdgcn_mfma_f32_16x16x32_bf16(aq[m], bq[n], acc[m][n], 0, 0, 0);
    __builtin_amdgcn_s_setprio(0);
    __builtin_amdgcn_sched_barrier(0);
    bi = (bi + 1 == NBUF) ? 0 : bi + 1;
    bs = (bs + 1 == NBUF) ? 0 : bs + 1;
  }

  const int cl = la;
  const int rg = lk * 4;
  const int rowbase = brow + wr * (MF * 16);
  const int colbase = bcol + wc * (NF * 16);

  if (MODE == 1 || MODE == 2) {
    unsigned short* Cb = C + (size_t)bz * sC;
#pragma unroll
    for (int m = 0; m < MF; m++) {
#pragma unroll
      for (int n = 0; n < NF; n++) {
        const int col = colbase + n * 16 + cl;
        const float bcv = (MODE == 1) ? auxA[col] : 0.f;
#pragma unroll
        for (int j = 0; j < 4; j++) {
          const int row = rowbase + m * 16 + rg + j;
          float v = acc[m][n][j] + bcv + ((MODE == 2) ? auxA[row] : 0.f);
          Cb[(size_t)row * N + col] = f2bf(v);
        }
      }
    }
  } else { // MODE 5
#pragma unroll
    for (int m = 0; m < MF; m++) {
      const int row = rowbase + m * 16 + rg;
      const int bb = row >> 12;
      const int p  = row & 4095;
#pragma unroll
      for (int n = 0; n < NF; n++) {
        const int col = colbase + n * 16 + cl;
        const size_t idx = ((size_t)bb * 512 + col) * 4096 + p;
        const float4 xv = *(const float4*)&auxA[idx];
        const float bv = auxB[col];
        float4 ov;
        ov.x = acc[m][n][0] + xv.x + bv;
        ov.y = acc[m][n][1] + xv.y + bv;
        ov.z = acc[m][n][2] + xv.z + bv;
        ov.w = acc[m][n][3] + xv.w + bv;
        *(float4*)&OUTF[idx] = ov;
      }
    }
  }
}

#define GEMM_ARGS const unsigned short* A, const unsigned short* B, unsigned short* C, \
                  float* OUTF, const float* auxA, const float* auxB, float* auxW, \
                  int M, int N, int K, float scale, size_t sA, size_t sB, size_t sC, int gx, int gy
#define GEMM_PASS A, B, C, OUTF, auxA, auxB, auxW, M, N, K, scale, sA, sB, sC, gx, gy

__global__ __launch_bounds__(512, 2) void k_qkproj(GEMM_ARGS){ gemm_body<1, 128>(GEMM_PASS); }
__global__ __launch_bounds__(512, 2) void k_vproj (GEMM_ARGS){ gemm_body<2, 128>(GEMM_PASS); }
__global__ __launch_bounds__(512, 2) void k_oproj (GEMM_ARGS){ gemm_body<5, 128>(GEMM_PASS); }

// ---------------- rowsum reduce ----------------
__global__ __launch_bounds__(256) void rowsum_inv(const float* __restrict__ partial,
                                                  float* __restrict__ rinv){
  const int idx = blockIdx.x * 256 + threadIdx.x;   // 16384
  const int b = idx >> 12, q = idx & 4095;
  const float* p = partial + ((size_t)b * 64) * 4096 + q;
  float s = 0.f;
#pragma unroll
  for (int i = 0; i < 64; i++) s += p[(size_t)i * 4096];
  rinv[idx] = 1.f / s;
}

// ---------------- PV split-K sum + rinv scale ----------------
__global__ __launch_bounds__(256) void pv_sum(const unsigned short* __restrict__ otp,
                                              const float* __restrict__ rinv,
                                              unsigned short* __restrict__ ot){
  const size_t e = ((size_t)blockIdx.x * 256 + threadIdx.x) * 8;   // < 8388608
  const float r = rinv[e >> 9];
  u16x8 a = *(const u16x8*)&otp[e];
  u16x8 b = *(const u16x8*)&otp[8388608 + e];
  u16x8 o;
#pragma unroll
  for (int j = 0; j < 8; j++) o[j] = f2bf((bf2f(a[j]) + bf2f(b[j])) * r);
  *(u16x8*)&ot[e] = o;
}

extern "C" void kernel_launch(void* const* d_in, const int* in_sizes, int n_in,
                              void* d_out, int out_size, void* d_ws, size_t ws_size,
                              hipStream_t stream) {
  const float* x     = (const float*)d_in[0];
  const float* mask  = (const float*)d_in[1];
  const float* gamma = (const float*)d_in[2];
  const float* beta  = (const float*)d_in[3];
  const float* Wq    = (const float*)d_in[4];
  const float* bq    = (const float*)d_in[5];
  const float* Wk    = (const float*)d_in[6];
  const float* bk    = (const float*)d_in[7];
  const float* Wv    = (const float*)d_in[8];
  const float* bv    = (const float*)d_in[9];
  const float* Wo    = (const float*)d_in[10];
  const float* bo    = (const float*)d_in[11];
  float* out = (float*)d_out;

  size_t off = 0;
  auto nxt = [&](size_t bytes) -> void* {
    void* p = (char*)d_ws + off;
    off += (bytes + 255) & ~(size_t)255;
    return p;
  };
  float* stats          = (float*)nxt(256 * sizeof(float));
  float* spart          = (float*)nxt(2048 * sizeof(float));
  float* partial        = (float*)nxt((size_t)4 * 64 * 4096 * 4);
  float* rinv           = (float*)nxt((size_t)16384 * 4);
  unsigned short* Wqb   = (unsigned short*)nxt((size_t)512 * 512 * 2);
  unsigned short* Wkb   = (unsigned short*)nxt((size_t)512 * 512 * 2);
  unsigned short* Wvb   = (unsigned short*)nxt((size_t)512 * 512 * 2);
  unsigned short* Wob   = (unsigned short*)nxt((size_t)512 * 512 * 2);
  unsigned short* hnt   = (unsigned short*)nxt((size_t)16384 * 512 * 2);
  unsigned short* qt    = (unsigned short*)nxt((size_t)16384 * 512 * 2);
  unsigned short* ktb   = (unsigned short*)nxt((size_t)16384 * 512 * 2);
  unsigned short* vcm   = (unsigned short*)nxt((size_t)16384 * 512 * 2);
  unsigned short* ot    = (unsigned short*)nxt((size_t)16384 * 512 * 2);
  unsigned short* otp   = (unsigned short*)nxt((size_t)2 * 8388608 * 2);  // split-K partials
  unsigned short* P     = (unsigned short*)nxt((size_t)4 * 4096 * 4096 * 2);

  conv4<<<512, 256, 0, stream>>>(Wq, Wk, Wv, Wo, Wqb, Wkb, Wvb, Wob);

  gn_stats1<<<1024, 256, 0, stream>>>(x, spart);
  gn_stats2<<<1, 128, 0, stream>>>(spart, stats);
  gn_apply<<<dim3(128, 16, 4), 256, 0, stream>>>(x, stats, gamma, beta, hnt);

  // Q, K: [16384,512] = hn_t x W^T (+ per-col bias); gx=64, gy=4 -> 256
  k_qkproj<<<256, 512, 0, stream>>>(hnt, Wqb, qt, nullptr, bq, nullptr, nullptr,
                                    16384, 512, 512, 1.f, 0, 0, 0, 64, 4);
  k_qkproj<<<256, 512, 0, stream>>>(hnt, Wkb, ktb, nullptr, bk, nullptr, nullptr,
                                    16384, 512, 512, 1.f, 0, 0, 0, 64, 4);
  // V channel-major: v_cm[b][c][p] (+ per-row bias); gx=2, gy=32, gz=4 -> 256
  k_vproj<<<256, 512, 0, stream>>>(Wvb, hnt, vcm, nullptr, bv, nullptr, nullptr,
                                   512, 4096, 512, 1.f,
                                   0, (size_t)4096 * 512, (size_t)512 * 4096, 2, 32);
  // scores: P_un = mask*exp(s*scale) (bf16) + row partial sums; gx=16, gy=16, gz=4 -> 1024
  gemm8<3><<<1024, 512, 0, stream>>>(qt, ktb, P, mask, partial,
                                     4096, 4096, 512, 512, 512, 0.044194173824159216f,
                                     (size_t)4096 * 512, (size_t)4096 * 512,
                                     (size_t)4096 * 4096, 16, 16);
  rowsum_inv<<<64, 256, 0, stream>>>(partial, rinv);
  // PV split-K=2: otp[ks][b][q][c] = P[b][q, ks*2048:+2048] x vcm[b][c, ...]^T
  // gx=16, gy=2, gz=8 (bz = ks*4+b) -> 256
  gemm8<6><<<256, 512, 0, stream>>>(P, vcm, otp, nullptr, nullptr,
                                    4096, 512, 2048, 4096, 4096, 1.f,
                                    (size_t)4096 * 4096, (size_t)512 * 4096,
                                    (size_t)4096 * 512, 16, 2);
  pv_sum<<<4096, 256, 0, stream>>>(otp, rinv, ot);
  // O-projection + residual + bias -> fp32 out; gx=64, gy=4 -> 256
  k_oproj<<<256, 512, 0, stream>>>(ot, Wob, nullptr, out, x, bo, nullptr,
                                   16384, 512, 512, 1.f, 0, 0, 0, 64, 4);
}

// Round 8
// 288.531 us; speedup vs baseline: 1.0991x; 1.0991x over previous
//
#include <hip/hip_runtime.h>
#include <hip/hip_bf16.h>
#include <stdint.h>

typedef __attribute__((ext_vector_type(4))) float f32x4;
typedef __attribute__((ext_vector_type(8))) __bf16 bf16x8;
typedef __attribute__((ext_vector_type(8))) unsigned short u16x8;

__device__ __forceinline__ unsigned short f2bf(float f){
  uint32_t u = __builtin_bit_cast(uint32_t, f);
  u += 0x7FFFu + ((u >> 16) & 1u);
  return (unsigned short)(u >> 16);
}
__device__ __forceinline__ float bf2f(unsigned short h){
  return __builtin_bit_cast(float, ((uint32_t)h) << 16);
}
__device__ __forceinline__ float fast_exp2(float x){
#if __has_builtin(__builtin_amdgcn_exp2f)
  return __builtin_amdgcn_exp2f(x);
#else
  return exp2f(x);
#endif
}
__device__ __forceinline__ void gl_lds16(const unsigned short* g, unsigned short* l){
  __builtin_amdgcn_global_load_lds(
      (const __attribute__((address_space(1))) uint32_t*)g,
      (__attribute__((address_space(3))) uint32_t*)l, 16, 0, 0);
}

// ---------------- fp32 -> bf16 convert: Wq|Wk -> concat, Wv, Wo ----------------
__global__ __launch_bounds__(256) void conv4(const float* __restrict__ a, const float* __restrict__ b,
                                             const float* __restrict__ c, const float* __restrict__ d,
                                             unsigned short* __restrict__ oqk,
                                             unsigned short* __restrict__ ov,
                                             unsigned short* __restrict__ oo){
  const int bid = blockIdx.x;            // 512 blocks; 128 per weight
  const int sel = bid >> 7;
  const float* in = sel == 0 ? a : sel == 1 ? b : sel == 2 ? c : d;
  unsigned short* out = sel == 0 ? oqk : sel == 1 ? (oqk + 262144) : sel == 2 ? ov : oo;
  const int i = ((bid & 127) * 256 + threadIdx.x) * 8;
  float4 v0 = *(const float4*)&in[i];
  float4 v1 = *(const float4*)&in[i + 4];
  u16x8 o;
  o[0]=f2bf(v0.x); o[1]=f2bf(v0.y); o[2]=f2bf(v0.z); o[3]=f2bf(v0.w);
  o[4]=f2bf(v1.x); o[5]=f2bf(v1.y); o[6]=f2bf(v1.z); o[7]=f2bf(v1.w);
  *(u16x8*)&out[i] = o;
}

// ---------------- GroupNorm stats, 2-stage ----------------
__global__ __launch_bounds__(256) void gn_stats1(const float* __restrict__ x,
                                                 float* __restrict__ part){
  const int bid = blockIdx.x;            // 1024 segments of 8192 floats
  const float* p = x + (size_t)bid * 8192;
  float s = 0.f, ss = 0.f;
  for (int i = threadIdx.x; i < 2048; i += 256) {
    float4 v = *(const float4*)(p + (size_t)i * 4);
    s  += v.x + v.y + v.z + v.w;
    ss += v.x*v.x + v.y*v.y + v.z*v.z + v.w*v.w;
  }
  for (int off = 32; off; off >>= 1) { s += __shfl_down(s, off); ss += __shfl_down(ss, off); }
  __shared__ float red[8];
  int w = threadIdx.x >> 6;
  if ((threadIdx.x & 63) == 0) { red[w] = s; red[w + 4] = ss; }
  __syncthreads();
  if (threadIdx.x == 0) {
    part[bid * 2]     = red[0] + red[1] + red[2] + red[3];
    part[bid * 2 + 1] = red[4] + red[5] + red[6] + red[7];
  }
}
__global__ __launch_bounds__(128) void gn_stats2(const float* __restrict__ part,
                                                 float* __restrict__ stats){
  const int g = threadIdx.x;             // 128 groups
  float s = 0.f, ss = 0.f;
#pragma unroll
  for (int i = 0; i < 8; i++) { s += part[(g * 8 + i) * 2]; ss += part[(g * 8 + i) * 2 + 1]; }
  float mean = s * (1.f / 65536.f);
  float var  = ss * (1.f / 65536.f) - mean * mean;
  stats[g * 2]     = mean;
  stats[g * 2 + 1] = rsqrtf(var + 1e-6f);
}

// ---------------- GN apply + transpose (64ch x 32px tiles, paired-ch writes) ----------------
__global__ __launch_bounds__(256) void gn_apply(const float* __restrict__ x,
                                                const float* __restrict__ stats,
                                                const float* __restrict__ gamma,
                                                const float* __restrict__ beta,
                                                unsigned short* __restrict__ hn_t){
  __shared__ float tile[64][33];
  const int b  = blockIdx.z;
  const int c0 = blockIdx.y * 64;
  const int p0 = blockIdx.x * 32;
  const int t  = threadIdx.x;
  const float* xb = x + (size_t)b * 512 * 4096;
  const int lpx = t & 31, lcc = t >> 5;
#pragma unroll
  for (int i = 0; i < 8; i++)
    tile[lcc + i * 8][lpx] = xb[(size_t)(c0 + lcc + i * 8) * 4096 + p0 + lpx];
  __syncthreads();
  unsigned short* hb = hn_t + (size_t)b * 4096 * 512;
  const int c   = c0 + (t & 31) * 2;     // even -> c,c+1 same 16-ch group
  const int pxi = t >> 5;                // 0..7
  const int g2  = (b * 32 + (c >> 4)) * 2;
  const float mean = stats[g2], rstd = stats[g2 + 1];
  const float ga0 = gamma[c], be0 = beta[c];
  const float ga1 = gamma[c + 1], be1 = beta[c + 1];
#pragma unroll
  for (int i = 0; i < 4; i++) {
    const int px = pxi + i * 8;
    float v0 = tile[(t & 31) * 2][px];
    float v1 = tile[(t & 31) * 2 + 1][px];
    uint32_t h0 = f2bf((v0 - mean) * rstd * ga0 + be0);
    uint32_t h1 = f2bf((v1 - mean) * rstd * ga1 + be1);
    *(uint32_t*)&hb[(size_t)(p0 + px) * 512 + c] = h0 | (h1 << 16);
  }
}

// ---------------- R5-structure GEMM (projections / PV): BM=256, BN=128, BK=64 ----------------
// 8 waves 2Mx4N, wave tile 128x32; 2 phases/K-tile, counted vmcnt(2)/(4).
// MODE 1: +bias(colsplit qk)->bf16 | 2: +bias[row]->bf16 | 4: acc*rinv[row]->bf16
// MODE 5: acc+resid+bias[col]->fp32 transposed
template<int MODE>
__device__ __forceinline__ void gemm_body5(
    const unsigned short* __restrict__ A, const unsigned short* __restrict__ B,
    unsigned short* __restrict__ C, float* __restrict__ OUTF,
    const float* __restrict__ auxA, const float* __restrict__ auxB,
    int M, int N, int K, float scale,
    size_t sA, size_t sB, size_t sC, int gx, int gy)
{
  constexpr int NF = 2;
  __shared__ __align__(16) unsigned short As[4 * 8192];
  __shared__ __align__(16) unsigned short Bs[2 * 8192];

  const int lin = blockIdx.x;
  const int nwg = gridDim.x;
  const int wg = ((lin & 7) * (nwg >> 3)) + (lin >> 3);
  const int bx = wg % gx;
  const int t2 = wg / gx;
  const int by = t2 % gy;
  const int bz = t2 / gy;

  const unsigned short* Ab = A + (size_t)bz * sA;
  const unsigned short* Bb = B + (size_t)bz * sB;
  const int brow = bx * 256;
  const int bcol = by * 128;
  const int t = threadIdx.x;
  const int lane = t & 63;
  const int wid = t >> 6;
  const int wr = wid >> 2;          // 0..1
  const int wc = wid & 3;           // 0..3
  const int la = lane & 15;
  const int lk = lane >> 4;
  const int axr = la >> 1;          // read-side slot XOR (0..7)

  const f32x4 zero = {0.f, 0.f, 0.f, 0.f};
  f32x4 acc[8][NF];
#pragma unroll
  for (int m = 0; m < 8; m++)
#pragma unroll
    for (int n = 0; n < NF; n++) acc[m][n] = zero;

  const int ru0 = t >> 3, s0 = t & 7;
  const int gx0 = s0 ^ ((ru0 >> 1) & 7);

  auto stageA = [&](int kt, int h) {
    unsigned short* base = As + ((kt & 1) * 2 + h) * 8192;
    const size_t ko = (size_t)kt * 64;
    gl_lds16(Ab + (size_t)(brow + h * 64 + ru0) * K + ko + gx0 * 8, base + t * 8);
    gl_lds16(Ab + (size_t)(brow + 128 + h * 64 + ru0) * K + ko + gx0 * 8, base + 4096 + t * 8);
  };
  auto stageBf = [&](int kt) {
    unsigned short* base = Bs + (kt & 1) * 8192;
    const size_t ko = (size_t)kt * 64;
    gl_lds16(Bb + (size_t)(bcol + ru0) * K + ko + gx0 * 8, base + t * 8);
    gl_lds16(Bb + (size_t)(bcol + 64 + ru0) * K + ko + gx0 * 8, base + 4096 + t * 8);
  };
  auto LDA = [&](int db, int mh, int i, int kst) -> bf16x8 {
    const int ru = wr * 64 + i * 16 + la;
    const int slot = ((kst << 2) | lk) ^ axr;
    return __builtin_bit_cast(bf16x8, *(const u16x8*)&As[(db * 2 + mh) * 8192 + ru * 64 + slot * 8]);
  };
  auto LDB = [&](int db, int n2, int kst) -> bf16x8 {
    const int ru = wc * 32 + n2 * 16 + la;
    const int slot = ((kst << 2) | lk) ^ axr;
    return __builtin_bit_cast(bf16x8, *(const u16x8*)&Bs[db * 8192 + ru * 64 + slot * 8]);
  };

#define DSR5(mh) \
  bf16x8 aq[4][2], bq[2][2]; \
  _Pragma("unroll") for (int i = 0; i < 4; ++i) { aq[i][0] = LDA(db, mh, i, 0); aq[i][1] = LDA(db, mh, i, 1); } \
  _Pragma("unroll") for (int n2 = 0; n2 < 2; ++n2) { bq[n2][0] = LDB(db, n2, 0); bq[n2][1] = LDB(db, n2, 1); }

#define MM5(mh) \
  asm volatile("s_waitcnt lgkmcnt(0)" ::: "memory"); \
  __builtin_amdgcn_sched_barrier(0); \
  __builtin_amdgcn_s_setprio(1); \
  _Pragma("unroll") for (int i = 0; i < 4; ++i) \
    _Pragma("unroll") for (int n2 = 0; n2 < 2; ++n2) { \
      acc[(mh)*4+i][n2] = __builtin_amdgcn_mfma_f32_16x16x32_bf16(aq[i][0], bq[n2][0], acc[(mh)*4+i][n2], 0, 0, 0); \
      acc[(mh)*4+i][n2] = __builtin_amdgcn_mfma_f32_16x16x32_bf16(aq[i][1], bq[n2][1], acc[(mh)*4+i][n2], 0, 0, 0); } \
  __builtin_amdgcn_s_setprio(0); \
  __builtin_amdgcn_sched_barrier(0);

#define PHASE5(VMS, mh, STG) do { \
  asm volatile("s_waitcnt vmcnt(" VMS ")" ::: "memory"); \
  __builtin_amdgcn_s_barrier(); \
  DSR5(mh); \
  STG; \
  MM5(mh); \
} while (0)

  const int nk = K >> 6;
  stageA(0, 0); stageBf(0); stageA(0, 1);
  for (int j = 0; j < nk - 1; ++j) {
    const int db = j & 1;
    PHASE5("2", 0, { stageA(j + 1, 0); stageBf(j + 1); });
    PHASE5("4", 1, { stageA(j + 1, 1); });
  }
  {
    const int db = (nk - 1) & 1;
    asm volatile("s_waitcnt vmcnt(0)" ::: "memory");
    __builtin_amdgcn_s_barrier();
    { DSR5(0); MM5(0); }
    { DSR5(1); MM5(1); }
  }
#undef PHASE5
#undef MM5
#undef DSR5

  // epilogue: C/D layout col=lane&15, row=(lane>>4)*4+j
  const int cl = la;
  const int rg = lk * 4;
  const int rowbase = brow + wr * 128;
  const int colbase = bcol + wc * 32;

  if (MODE == 1 || MODE == 2) {
    unsigned short* Cb = C + (size_t)bz * sC;
#pragma unroll
    for (int m = 0; m < 8; m++) {
#pragma unroll
      for (int n = 0; n < NF; n++) {
        const int col = colbase + n * 16 + cl;
        const float bcv = (MODE == 1) ? (col < 512 ? auxA[col] : auxB[col - 512]) : 0.f;
#pragma unroll
        for (int j = 0; j < 4; j++) {
          const int row = rowbase + m * 16 + rg + j;
          float v = acc[m][n][j] + bcv + ((MODE == 2) ? auxA[row] : 0.f);
          Cb[(size_t)row * N + col] = f2bf(v);
        }
      }
    }
  } else if (MODE == 4) {
    unsigned short* Cb = C + (size_t)bz * sC;
    const float* rb = auxA + (size_t)bz * 4096;
#pragma unroll
    for (int m = 0; m < 8; m++) {
      const float4 ri = *(const float4*)&rb[rowbase + m * 16 + rg];
      const float riv[4] = {ri.x, ri.y, ri.z, ri.w};
#pragma unroll
      for (int n = 0; n < NF; n++) {
        const int col = colbase + n * 16 + cl;
#pragma unroll
        for (int j = 0; j < 4; j++) {
          const int row = rowbase + m * 16 + rg + j;
          Cb[(size_t)row * N + col] = f2bf(acc[m][n][j] * riv[j]);
        }
      }
    }
  } else { // MODE 5
#pragma unroll
    for (int m = 0; m < 8; m++) {
      const int row = rowbase + m * 16 + rg;
      const int bb = row >> 12;
      const int p  = row & 4095;
#pragma unroll
      for (int n = 0; n < NF; n++) {
        const int col = colbase + n * 16 + cl;
        const size_t idx = ((size_t)bb * 512 + col) * 4096 + p;
        const float4 xv = *(const float4*)&auxA[idx];
        const float bv = auxB[col];
        float4 ov;
        ov.x = acc[m][n][0] + xv.x + bv;
        ov.y = acc[m][n][1] + xv.y + bv;
        ov.z = acc[m][n][2] + xv.z + bv;
        ov.w = acc[m][n][3] + xv.w + bv;
        *(float4*)&OUTF[idx] = ov;
      }
    }
  }
}

#define GEMM_ARGS const unsigned short* A, const unsigned short* B, unsigned short* C, \
                  float* OUTF, const float* auxA, const float* auxB, \
                  int M, int N, int K, float scale, size_t sA, size_t sB, size_t sC, int gx, int gy
#define GEMM_PASS A, B, C, OUTF, auxA, auxB, M, N, K, scale, sA, sB, sC, gx, gy

__global__ __launch_bounds__(512, 2) void k_qkproj(GEMM_ARGS){ gemm_body5<1>(GEMM_PASS); }
__global__ __launch_bounds__(512, 2) void k_vproj (GEMM_ARGS){ gemm_body5<2>(GEMM_PASS); }
__global__ __launch_bounds__(512, 2) void k_pv    (GEMM_ARGS){ gemm_body5<4>(GEMM_PASS); }
__global__ __launch_bounds__(512, 2) void k_oproj (GEMM_ARGS){ gemm_body5<5>(GEMM_PASS); }

// ---------------- R6-structure scores GEMM: BM=BN=256, BK=32, NBUF=4 circular ----------------
// 8 waves 2Mx4N (wave tile 128x64); 1 barrier/K-tile; stage j+2 post-read; vmcnt(4).
// Epilogue: P = mask*exp2(acc*sc) -> bf16 + per-(block,wave) row partial sums.
__global__ __launch_bounds__(512, 2)
void k_scores(const unsigned short* __restrict__ A, const unsigned short* __restrict__ B,
              unsigned short* __restrict__ C, const float* __restrict__ mask,
              float* __restrict__ partial,
              int M, int N, int K, int ldA, int ldB, float scale,
              size_t sA, size_t sB, size_t sC, int gx, int gy)
{
  __shared__ __align__(16) unsigned short As[4 * 8192];
  __shared__ __align__(16) unsigned short Bs[4 * 8192];

  const int lin = blockIdx.x;
  const int nwg = gridDim.x;
  const int wg = ((lin & 7) * (nwg >> 3)) + (lin >> 3);
  const int bx = wg % gx;
  const int t2 = wg / gx;
  const int by = t2 % gy;
  const int bz = t2 / gy;

  const unsigned short* Ab = A + (size_t)bz * sA;
  const unsigned short* Bb = B + (size_t)bz * sB;
  const int brow = bx * 256;
  const int bcol = by * 256;
  const int t = threadIdx.x;
  const int lane = t & 63;
  const int wid = t >> 6;
  const int wr = wid >> 2;        // 0..1
  const int wc = wid & 3;         // 0..3
  const int la = lane & 15;
  const int lk = lane >> 4;
  const int axr = (la >> 1) & 3;

  const f32x4 zero = {0.f, 0.f, 0.f, 0.f};
  f32x4 acc[8][4];
#pragma unroll
  for (int m = 0; m < 8; m++)
#pragma unroll
    for (int n = 0; n < 4; n++) acc[m][n] = zero;

  const unsigned short* srcA[2];
  const unsigned short* srcB[2];
#pragma unroll
  for (int c = 0; c < 2; ++c) {
    const int q = c * 512 + t, r = q >> 2, s = (q & 3) ^ ((r >> 1) & 3);
    srcA[c] = Ab + (size_t)(brow + r) * ldA + s * 8;
    srcB[c] = Bb + (size_t)(bcol + r) * ldB + s * 8;
  }

  auto STAGE = [&](int kt, int buf) {
    const int ko = kt * 32;
#pragma unroll
    for (int c = 0; c < 2; ++c)
      gl_lds16(srcA[c] + ko, &As[buf * 8192 + (c * 512 + t) * 8]);
#pragma unroll
    for (int c = 0; c < 2; ++c)
      gl_lds16(srcB[c] + ko, &Bs[buf * 8192 + (c * 512 + t) * 8]);
  };
  auto LDA = [&](int buf, int m) -> bf16x8 {
    const int ru = wr * 128 + m * 16 + la;
    return __builtin_bit_cast(bf16x8, *(const u16x8*)&As[buf * 8192 + ru * 32 + ((lk ^ axr) * 8)]);
  };
  auto LDB = [&](int buf, int n) -> bf16x8 {
    const int ru = wc * 64 + n * 16 + la;
    return __builtin_bit_cast(bf16x8, *(const u16x8*)&Bs[buf * 8192 + ru * 32 + ((lk ^ axr) * 8)]);
  };

  const int nk = K >> 5;
  STAGE(0, 0);
  STAGE(1, 1);
  for (int j = 0; j < nk; ++j) {
    const int bi = j & 3, bs = (j + 2) & 3;
    if (j == nk - 1) asm volatile("s_waitcnt vmcnt(0)" ::: "memory");
    else             asm volatile("s_waitcnt vmcnt(4)" ::: "memory");
    __builtin_amdgcn_s_barrier();
    __builtin_amdgcn_sched_barrier(0);
    bf16x8 bq[4], aq[8];
#pragma unroll
    for (int n = 0; n < 4; n++) bq[n] = LDB(bi, n);
#pragma unroll
    for (int m = 0; m < 8; m++) aq[m] = LDA(bi, m);
    if (j + 2 < nk) STAGE(j + 2, bs);
    asm volatile("s_waitcnt lgkmcnt(0)" ::: "memory");
    __builtin_amdgcn_sched_barrier(0);
    __builtin_amdgcn_s_setprio(1);
#pragma unroll
    for (int m = 0; m < 8; m++)
#pragma unroll
      for (int n = 0; n < 4; n++)
        acc[m][n] = __builtin_amdgcn_mfma_f32_16x16x32_bf16(aq[m], bq[n], acc[m][n], 0, 0, 0);
    __builtin_amdgcn_s_setprio(0);
    __builtin_amdgcn_sched_barrier(0);
  }

  // epilogue
  const int cl = la;
  const int rg = lk * 4;
  const int rowbase = brow + wr * 128;
  const int colbase = bcol + wc * 64;
  unsigned short* Cb = C + (size_t)bz * sC;
  const float* maskb = mask + (size_t)bz * 4096;
  float* partb = partial + ((size_t)bz * 64 + (size_t)(by * 4 + wc)) * M;
  const float sc2 = scale * 1.4426950408889634f;
  f32x4 rs[8];
#pragma unroll
  for (int m = 0; m < 8; m++) rs[m] = zero;
#pragma unroll
  for (int m = 0; m < 8; m++) {
#pragma unroll
    for (int n = 0; n < 4; n++) {
      const int col = colbase + n * 16 + cl;
      const float mk = maskb[col];
#pragma unroll
      for (int j = 0; j < 4; j++) {
        const int row = rowbase + m * 16 + rg + j;
        float v = mk * fast_exp2(acc[m][n][j] * sc2);
        rs[m][j] += v;
        Cb[(size_t)row * N + col] = f2bf(v);
      }
    }
  }
#pragma unroll
  for (int off = 1; off < 16; off <<= 1)
#pragma unroll
    for (int m = 0; m < 8; m++) {
#pragma unroll
      for (int j = 0; j < 4; j++) rs[m][j] += __shfl_xor(rs[m][j], off);
    }
  if (cl == 0) {
#pragma unroll
    for (int m = 0; m < 8; m++) {
      float4 v = make_float4(rs[m][0], rs[m][1], rs[m][2], rs[m][3]);
      *(float4*)&partb[rowbase + m * 16 + rg] = v;
    }
  }
}

// ---------------- rowsum reduce ----------------
__global__ __launch_bounds__(256) void rowsum_inv(const float* __restrict__ partial,
                                                  float* __restrict__ rinv){
  const int idx = blockIdx.x * 256 + threadIdx.x;   // 16384
  const int b = idx >> 12, q = idx & 4095;
  const float* p = partial + ((size_t)b * 64) * 4096 + q;
  float s = 0.f;
#pragma unroll
  for (int i = 0; i < 64; i++) s += p[(size_t)i * 4096];
  rinv[idx] = 1.f / s;
}

extern "C" void kernel_launch(void* const* d_in, const int* in_sizes, int n_in,
                              void* d_out, int out_size, void* d_ws, size_t ws_size,
                              hipStream_t stream) {
  const float* x     = (const float*)d_in[0];
  const float* mask  = (const float*)d_in[1];
  const float* gamma = (const float*)d_in[2];
  const float* beta  = (const float*)d_in[3];
  const float* Wq    = (const float*)d_in[4];
  const float* bq    = (const float*)d_in[5];
  const float* Wk    = (const float*)d_in[6];
  const float* bk    = (const float*)d_in[7];
  const float* Wv    = (const float*)d_in[8];
  const float* bv    = (const float*)d_in[9];
  const float* Wo    = (const float*)d_in[10];
  const float* bo    = (const float*)d_in[11];
  float* out = (float*)d_out;

  size_t off = 0;
  auto nxt = [&](size_t bytes) -> void* {
    void* p = (char*)d_ws + off;
    off += (bytes + 255) & ~(size_t)255;
    return p;
  };
  float* stats          = (float*)nxt(256 * sizeof(float));
  float* spart          = (float*)nxt(2048 * sizeof(float));
  float* partial        = (float*)nxt((size_t)4 * 64 * 4096 * 4);
  float* rinv           = (float*)nxt((size_t)16384 * 4);
  unsigned short* Wqkb  = (unsigned short*)nxt((size_t)1024 * 512 * 2);
  unsigned short* Wvb   = (unsigned short*)nxt((size_t)512 * 512 * 2);
  unsigned short* Wob   = (unsigned short*)nxt((size_t)512 * 512 * 2);
  unsigned short* hnt   = (unsigned short*)nxt((size_t)16384 * 512 * 2);  // [b*4096+p][c]
  unsigned short* qkt   = (unsigned short*)nxt((size_t)16384 * 1024 * 2); // [b*4096+p][q|k]
  unsigned short* vcm   = (unsigned short*)nxt((size_t)16384 * 512 * 2);  // [b][c][p]
  unsigned short* ot    = (unsigned short*)nxt((size_t)16384 * 512 * 2);  // [b*4096+p][c]
  unsigned short* P     = (unsigned short*)nxt((size_t)4 * 4096 * 4096 * 2);

  conv4<<<512, 256, 0, stream>>>(Wq, Wk, Wv, Wo, Wqkb, Wvb, Wob);

  gn_stats1<<<1024, 256, 0, stream>>>(x, spart);
  gn_stats2<<<1, 128, 0, stream>>>(spart, stats);
  gn_apply<<<dim3(128, 8, 4), 256, 0, stream>>>(x, stats, gamma, beta, hnt);

  // fused QK proj: qkt[16384][1024] = hn_t x (Wq|Wk)^T (+ bq|bk); gx=64, gy=8 -> 512
  k_qkproj<<<512, 512, 0, stream>>>(hnt, Wqkb, qkt, nullptr, bq, bk,
                                    16384, 1024, 512, 1.f, 0, 0, 0, 64, 8);
  // V channel-major: v_cm[b][c][p] (+ per-row bias); gx=2, gy=32, gz=4 -> 256
  k_vproj<<<256, 512, 0, stream>>>(Wvb, hnt, vcm, nullptr, bv, nullptr,
                                   512, 4096, 512, 1.f,
                                   0, (size_t)4096 * 512, (size_t)512 * 4096, 2, 32);
  // scores: P = mask*exp(s*scale) (bf16) + row partial sums; gx=16, gy=16, gz=4 -> 1024
  k_scores<<<1024, 512, 0, stream>>>(qkt, qkt + 512, P, mask, partial,
                                     4096, 4096, 512, 1024, 1024, 0.044194173824159216f,
                                     (size_t)4096 * 1024, (size_t)4096 * 1024,
                                     (size_t)4096 * 4096, 16, 16);
  rowsum_inv<<<64, 256, 0, stream>>>(partial, rinv);
  // PV: ot[b][qi][c] = (P x v_cm^T) * rinv[qi]; gx=16, gy=4, gz=4 -> 256
  k_pv<<<256, 512, 0, stream>>>(P, vcm, ot, nullptr, rinv, nullptr,
                                4096, 512, 4096, 1.f,
                                (size_t)4096 * 4096, (size_t)512 * 4096,
                                (size_t)4096 * 512, 16, 4);
  // O-projection + residual + bias -> fp32 out; gx=64, gy=4 -> 256
  k_oproj<<<256, 512, 0, stream>>>(ot, Wob, nullptr, out, x, bo,
                                   16384, 512, 512, 1.f, 0, 0, 0, 64, 4);
}

// Round 9
// 255.774 us; speedup vs baseline: 1.2398x; 1.1281x over previous
//
#include <hip/hip_runtime.h>
#include <hip/hip_bf16.h>
#include <stdint.h>

typedef __attribute__((ext_vector_type(4))) float f32x4;
typedef __attribute__((ext_vector_type(8))) __bf16 bf16x8;
typedef __attribute__((ext_vector_type(8))) unsigned short u16x8;
typedef long long ll64;

__device__ __forceinline__ unsigned short f2bf(float f){
  uint32_t u = __builtin_bit_cast(uint32_t, f);
  u += 0x7FFFu + ((u >> 16) & 1u);
  return (unsigned short)(u >> 16);
}
__device__ __forceinline__ float bf2f(unsigned short h){
  return __builtin_bit_cast(float, ((uint32_t)h) << 16);
}
__device__ __forceinline__ float fast_exp2(float x){
#if __has_builtin(__builtin_amdgcn_exp2f)
  return __builtin_amdgcn_exp2f(x);
#else
  return exp2f(x);
#endif
}
__device__ __forceinline__ unsigned char f2fp8(float f){
#if __has_builtin(__builtin_amdgcn_cvt_pk_fp8_f32)
  int r = __builtin_amdgcn_cvt_pk_fp8_f32(f, f, 0, false);
  return (unsigned char)(r & 0xff);
#else
  uint32_t u = __builtin_bit_cast(uint32_t, f);
  uint32_t s = (u >> 24) & 0x80u;
  uint32_t a = u & 0x7fffffffu;
  float af = __builtin_bit_cast(float, a);
  if (af >= 448.f) return (unsigned char)(s | 0x7e);
  a += 0x000fffffu + ((a >> 20) & 1u);
  int e = (int)(a >> 23) - 127;
  if (e < -6) return (unsigned char)s;
  return (unsigned char)(s | (uint32_t)((e + 7) << 3) | ((a >> 20) & 7u));
#endif
}
__device__ __forceinline__ void gl_lds16(const unsigned short* g, unsigned short* l){
  __builtin_amdgcn_global_load_lds(
      (const __attribute__((address_space(1))) uint32_t*)g,
      (__attribute__((address_space(3))) uint32_t*)l, 16, 0, 0);
}
__device__ __forceinline__ void gl_lds16b(const unsigned char* g, unsigned char* l){
  __builtin_amdgcn_global_load_lds(
      (const __attribute__((address_space(1))) uint32_t*)g,
      (__attribute__((address_space(3))) uint32_t*)l, 16, 0, 0);
}

// ---------------- fp32 -> bf16 convert: Wq|Wk concat, Wv, Wo ----------------
__global__ __launch_bounds__(256) void conv4(const float* __restrict__ a, const float* __restrict__ b,
                                             const float* __restrict__ c, const float* __restrict__ d,
                                             unsigned short* __restrict__ oqk,
                                             unsigned short* __restrict__ ov,
                                             unsigned short* __restrict__ oo){
  const int bid = blockIdx.x;
  const int sel = bid >> 7;
  const float* in = sel == 0 ? a : sel == 1 ? b : sel == 2 ? c : d;
  unsigned short* out = sel == 0 ? oqk : sel == 1 ? (oqk + 262144) : sel == 2 ? ov : oo;
  const int i = ((bid & 127) * 256 + threadIdx.x) * 8;
  float4 v0 = *(const float4*)&in[i];
  float4 v1 = *(const float4*)&in[i + 4];
  u16x8 o;
  o[0]=f2bf(v0.x); o[1]=f2bf(v0.y); o[2]=f2bf(v0.z); o[3]=f2bf(v0.w);
  o[4]=f2bf(v1.x); o[5]=f2bf(v1.y); o[6]=f2bf(v1.z); o[7]=f2bf(v1.w);
  *(u16x8*)&out[i] = o;
}

// ---------------- GroupNorm stats, 2-stage ----------------
__global__ __launch_bounds__(256) void gn_stats1(const float* __restrict__ x,
                                                 float* __restrict__ part){
  const int bid = blockIdx.x;
  const float* p = x + (size_t)bid * 8192;
  float s = 0.f, ss = 0.f;
  for (int i = threadIdx.x; i < 2048; i += 256) {
    float4 v = *(const float4*)(p + (size_t)i * 4);
    s  += v.x + v.y + v.z + v.w;
    ss += v.x*v.x + v.y*v.y + v.z*v.z + v.w*v.w;
  }
  for (int off = 32; off; off >>= 1) { s += __shfl_down(s, off); ss += __shfl_down(ss, off); }
  __shared__ float red[8];
  int w = threadIdx.x >> 6;
  if ((threadIdx.x & 63) == 0) { red[w] = s; red[w + 4] = ss; }
  __syncthreads();
  if (threadIdx.x == 0) {
    part[bid * 2]     = red[0] + red[1] + red[2] + red[3];
    part[bid * 2 + 1] = red[4] + red[5] + red[6] + red[7];
  }
}
__global__ __launch_bounds__(128) void gn_stats2(const float* __restrict__ part,
                                                 float* __restrict__ stats){
  const int g = threadIdx.x;
  float s = 0.f, ss = 0.f;
#pragma unroll
  for (int i = 0; i < 8; i++) { s += part[(g * 8 + i) * 2]; ss += part[(g * 8 + i) * 2 + 1]; }
  float mean = s * (1.f / 65536.f);
  float var  = ss * (1.f / 65536.f) - mean * mean;
  stats[g * 2]     = mean;
  stats[g * 2 + 1] = rsqrtf(var + 1e-6f);
}

// ---------------- GN apply + transpose ----------------
__global__ __launch_bounds__(256) void gn_apply(const float* __restrict__ x,
                                                const float* __restrict__ stats,
                                                const float* __restrict__ gamma,
                                                const float* __restrict__ beta,
                                                unsigned short* __restrict__ hn_t){
  __shared__ float tile[64][33];
  const int b  = blockIdx.z;
  const int c0 = blockIdx.y * 64;
  const int p0 = blockIdx.x * 32;
  const int t  = threadIdx.x;
  const float* xb = x + (size_t)b * 512 * 4096;
  const int lpx = t & 31, lcc = t >> 5;
#pragma unroll
  for (int i = 0; i < 8; i++)
    tile[lcc + i * 8][lpx] = xb[(size_t)(c0 + lcc + i * 8) * 4096 + p0 + lpx];
  __syncthreads();
  unsigned short* hb = hn_t + (size_t)b * 4096 * 512;
  const int c   = c0 + (t & 31) * 2;
  const int pxi = t >> 5;
  const int g2  = (b * 32 + (c >> 4)) * 2;
  const float mean = stats[g2], rstd = stats[g2 + 1];
  const float ga0 = gamma[c], be0 = beta[c];
  const float ga1 = gamma[c + 1], be1 = beta[c + 1];
#pragma unroll
  for (int i = 0; i < 4; i++) {
    const int px = pxi + i * 8;
    float v0 = tile[(t & 31) * 2][px];
    float v1 = tile[(t & 31) * 2 + 1][px];
    uint32_t h0 = f2bf((v0 - mean) * rstd * ga0 + be0);
    uint32_t h1 = f2bf((v1 - mean) * rstd * ga1 + be1);
    *(uint32_t*)&hb[(size_t)(p0 + px) * 512 + c] = h0 | (h1 << 16);
  }
}

// ---------------- R5-structure bf16 GEMM (projections): BM=256, BN=128, BK=64 ----------------
// MODE 1: +bias(qk split) -> FP8 to qt8/kt8 | 2: +bias[row] -> FP8 to vcm8
// MODE 5: acc+resid+bias[col] -> fp32 transposed out
template<int MODE>
__device__ __forceinline__ void gemm_body5(
    const unsigned short* __restrict__ A, const unsigned short* __restrict__ B,
    unsigned char* __restrict__ C8, float* __restrict__ OUTF,
    const float* __restrict__ auxA, const float* __restrict__ auxB,
    int M, int N, int K, size_t sA, size_t sB, size_t sC, int gx, int gy)
{
  constexpr int NF = 2;
  __shared__ __align__(16) unsigned short As[4 * 8192];
  __shared__ __align__(16) unsigned short Bs[2 * 8192];

  const int lin = blockIdx.x;
  const int nwg = gridDim.x;
  const int wg = ((lin & 7) * (nwg >> 3)) + (lin >> 3);
  const int bx = wg % gx;
  const int t2 = wg / gx;
  const int by = t2 % gy;
  const int bz = t2 / gy;

  const unsigned short* Ab = A + (size_t)bz * sA;
  const unsigned short* Bb = B + (size_t)bz * sB;
  const int brow = bx * 256;
  const int bcol = by * 128;
  const int t = threadIdx.x;
  const int lane = t & 63;
  const int wid = t >> 6;
  const int wr = wid >> 2;
  const int wc = wid & 3;
  const int la = lane & 15;
  const int lk = lane >> 4;
  const int axr = la >> 1;

  const f32x4 zero = {0.f, 0.f, 0.f, 0.f};
  f32x4 acc[8][NF];
#pragma unroll
  for (int m = 0; m < 8; m++)
#pragma unroll
    for (int n = 0; n < NF; n++) acc[m][n] = zero;

  const int ru0 = t >> 3, s0 = t & 7;
  const int gx0 = s0 ^ ((ru0 >> 1) & 7);

  auto stageA = [&](int kt, int h) {
    unsigned short* base = As + ((kt & 1) * 2 + h) * 8192;
    const size_t ko = (size_t)kt * 64;
    gl_lds16(Ab + (size_t)(brow + h * 64 + ru0) * K + ko + gx0 * 8, base + t * 8);
    gl_lds16(Ab + (size_t)(brow + 128 + h * 64 + ru0) * K + ko + gx0 * 8, base + 4096 + t * 8);
  };
  auto stageBf = [&](int kt) {
    unsigned short* base = Bs + (kt & 1) * 8192;
    const size_t ko = (size_t)kt * 64;
    gl_lds16(Bb + (size_t)(bcol + ru0) * K + ko + gx0 * 8, base + t * 8);
    gl_lds16(Bb + (size_t)(bcol + 64 + ru0) * K + ko + gx0 * 8, base + 4096 + t * 8);
  };
  auto LDA = [&](int db, int mh, int i, int kst) -> bf16x8 {
    const int ru = wr * 64 + i * 16 + la;
    const int slot = ((kst << 2) | lk) ^ axr;
    return __builtin_bit_cast(bf16x8, *(const u16x8*)&As[(db * 2 + mh) * 8192 + ru * 64 + slot * 8]);
  };
  auto LDB = [&](int db, int n2, int kst) -> bf16x8 {
    const int ru = wc * 32 + n2 * 16 + la;
    const int slot = ((kst << 2) | lk) ^ axr;
    return __builtin_bit_cast(bf16x8, *(const u16x8*)&Bs[db * 8192 + ru * 64 + slot * 8]);
  };

#define DSR5(mh) \
  bf16x8 aq[4][2], bq[2][2]; \
  _Pragma("unroll") for (int i = 0; i < 4; ++i) { aq[i][0] = LDA(db, mh, i, 0); aq[i][1] = LDA(db, mh, i, 1); } \
  _Pragma("unroll") for (int n2 = 0; n2 < 2; ++n2) { bq[n2][0] = LDB(db, n2, 0); bq[n2][1] = LDB(db, n2, 1); }

#define MM5(mh) \
  asm volatile("s_waitcnt lgkmcnt(0)" ::: "memory"); \
  __builtin_amdgcn_sched_barrier(0); \
  __builtin_amdgcn_s_setprio(1); \
  _Pragma("unroll") for (int i = 0; i < 4; ++i) \
    _Pragma("unroll") for (int n2 = 0; n2 < 2; ++n2) { \
      acc[(mh)*4+i][n2] = __builtin_amdgcn_mfma_f32_16x16x32_bf16(aq[i][0], bq[n2][0], acc[(mh)*4+i][n2], 0, 0, 0); \
      acc[(mh)*4+i][n2] = __builtin_amdgcn_mfma_f32_16x16x32_bf16(aq[i][1], bq[n2][1], acc[(mh)*4+i][n2], 0, 0, 0); } \
  __builtin_amdgcn_s_setprio(0); \
  __builtin_amdgcn_sched_barrier(0);

#define PHASE5(VMS, mh, STG) do { \
  asm volatile("s_waitcnt vmcnt(" VMS ")" ::: "memory"); \
  __builtin_amdgcn_s_barrier(); \
  DSR5(mh); \
  STG; \
  MM5(mh); \
} while (0)

  const int nk = K >> 6;
  stageA(0, 0); stageBf(0); stageA(0, 1);
  for (int j = 0; j < nk - 1; ++j) {
    const int db = j & 1;
    PHASE5("2", 0, { stageA(j + 1, 0); stageBf(j + 1); });
    PHASE5("4", 1, { stageA(j + 1, 1); });
  }
  {
    const int db = (nk - 1) & 1;
    asm volatile("s_waitcnt vmcnt(0)" ::: "memory");
    __builtin_amdgcn_s_barrier();
    { DSR5(0); MM5(0); }
    { DSR5(1); MM5(1); }
  }
#undef PHASE5
#undef MM5
#undef DSR5

  const int cl = la;
  const int rg = lk * 4;
  const int rowbase = brow + wr * 128;
  const int colbase = bcol + wc * 32;

  if (MODE == 1) {
    // C8: qt8 (16384x512) then kt8 at +8388608
#pragma unroll
    for (int m = 0; m < 8; m++) {
#pragma unroll
      for (int n = 0; n < NF; n++) {
        const int col = colbase + n * 16 + cl;
        const float bcv = (col < 512 ? auxA[col] : auxB[col - 512]);
        unsigned char* dst = C8 + (col < 512 ? 0 : (size_t)8388608);
        const int c9 = col & 511;
#pragma unroll
        for (int j = 0; j < 4; j++) {
          const int row = rowbase + m * 16 + rg + j;
          dst[(size_t)row * 512 + c9] = f2fp8(acc[m][n][j] + bcv);
        }
      }
    }
  } else if (MODE == 2) {
    unsigned char* Cb = C8 + (size_t)bz * sC;
#pragma unroll
    for (int m = 0; m < 8; m++) {
#pragma unroll
      for (int n = 0; n < NF; n++) {
        const int col = colbase + n * 16 + cl;
#pragma unroll
        for (int j = 0; j < 4; j++) {
          const int row = rowbase + m * 16 + rg + j;
          Cb[(size_t)row * N + col] = f2fp8(acc[m][n][j] + auxA[row]);
        }
      }
    }
  } else { // MODE 5
#pragma unroll
    for (int m = 0; m < 8; m++) {
      const int row = rowbase + m * 16 + rg;
      const int bb = row >> 12;
      const int p  = row & 4095;
#pragma unroll
      for (int n = 0; n < NF; n++) {
        const int col = colbase + n * 16 + cl;
        const size_t idx = ((size_t)bb * 512 + col) * 4096 + p;
        const float4 xv = *(const float4*)&auxA[idx];
        const float bv = auxB[col];
        float4 ov;
        ov.x = acc[m][n][0] + xv.x + bv;
        ov.y = acc[m][n][1] + xv.y + bv;
        ov.z = acc[m][n][2] + xv.z + bv;
        ov.w = acc[m][n][3] + xv.w + bv;
        *(float4*)&OUTF[idx] = ov;
      }
    }
  }
}

#define GEMM_ARGS const unsigned short* A, const unsigned short* B, unsigned char* C8, \
                  float* OUTF, const float* auxA, const float* auxB, \
                  int M, int N, int K, size_t sA, size_t sB, size_t sC, int gx, int gy
#define GEMM_PASS A, B, C8, OUTF, auxA, auxB, M, N, K, sA, sB, sC, gx, gy

__global__ __launch_bounds__(512, 2) void k_qkproj(GEMM_ARGS){ gemm_body5<1>(GEMM_PASS); }
__global__ __launch_bounds__(512, 2) void k_vproj (GEMM_ARGS){ gemm_body5<2>(GEMM_PASS); }

// O-projection stays bf16 (A=ot bf16, B=Wob bf16), fp32 transposed out
__global__ __launch_bounds__(512, 2) void k_oproj(const unsigned short* A, const unsigned short* B,
                                                  float* OUTF, const float* resid, const float* bias,
                                                  int gx, int gy){
  gemm_body5<5>(A, B, nullptr, OUTF, resid, bias, 16384, 512, 512, 0, 0, 0, gx, gy);
}

// ---------------- fp8 scores GEMM: BM=BN=256, BK=64 fp8, NBUF=4 circular ----------------
// 8 waves 2Mx4N (wave tile 128x64); 1 barrier/K-tile; stage j+2 post-read; vmcnt(4).
// Epilogue: P = fp8(mask*exp2(acc*sc)) + per-(block,wave) row partial sums (f32).
__global__ __launch_bounds__(512, 2)
void k_scores(const unsigned char* __restrict__ A, const unsigned char* __restrict__ B,
              unsigned char* __restrict__ C, const float* __restrict__ mask,
              float* __restrict__ partial,
              int M, int N, int K, int ldA, int ldB, float scale,
              size_t sA, size_t sB, size_t sC, int gx, int gy)
{
  __shared__ __align__(16) unsigned char As[4 * 16384];   // 64 KB
  __shared__ __align__(16) unsigned char Bs[4 * 16384];   // 64 KB

  const int lin = blockIdx.x;
  const int nwg = gridDim.x;
  const int wg = ((lin & 7) * (nwg >> 3)) + (lin >> 3);
  const int bx = wg % gx;
  const int t2 = wg / gx;
  const int by = t2 % gy;
  const int bz = t2 / gy;

  const unsigned char* Ab = A + (size_t)bz * sA;
  const unsigned char* Bb = B + (size_t)bz * sB;
  const int brow = bx * 256;
  const int bcol = by * 256;
  const int t = threadIdx.x;
  const int lane = t & 63;
  const int wid = t >> 6;
  const int wr = wid >> 2;
  const int wc = wid & 3;
  const int la = lane & 15;
  const int lk = lane >> 4;

  const f32x4 zero = {0.f, 0.f, 0.f, 0.f};
  f32x4 acc[8][4];
#pragma unroll
  for (int m = 0; m < 8; m++)
#pragma unroll
    for (int n = 0; n < 4; n++) acc[m][n] = zero;

  // stage: tile = 256 rows x 64 B; 1024 chunks of 16B; thread does chunks t, 512+t
  const unsigned char* srcA[2];
  const unsigned char* srcB[2];
#pragma unroll
  for (int c = 0; c < 2; ++c) {
    const int q = c * 512 + t, r = q >> 2, s = (q & 3) ^ ((r >> 1) & 3);
    srcA[c] = Ab + (size_t)(brow + r) * ldA + s * 16;
    srcB[c] = Bb + (size_t)(bcol + r) * ldB + s * 16;
  }
  auto STAGE = [&](int kt, int buf) {
    const int ko = kt * 64;
#pragma unroll
    for (int c = 0; c < 2; ++c) {
      gl_lds16b(srcA[c] + ko, &As[buf * 16384 + (c * 512 + t) * 16]);
      gl_lds16b(srcB[c] + ko, &Bs[buf * 16384 + (c * 512 + t) * 16]);
    }
  };
  // frag read: row ru, k-byte = kst*32 + lk*8; slot XOR (ru>>1)&3
  auto LDA8 = [&](int buf, int m, int kst) -> ll64 {
    const int ru = wr * 128 + m * 16 + la;
    const int slot = ((kst << 1) | (lk >> 1)) ^ ((ru >> 1) & 3);
    return *(const ll64*)&As[buf * 16384 + ru * 64 + slot * 16 + (lk & 1) * 8];
  };
  auto LDB8 = [&](int buf, int n, int kst) -> ll64 {
    const int ru = wc * 64 + n * 16 + la;
    const int slot = ((kst << 1) | (lk >> 1)) ^ ((ru >> 1) & 3);
    return *(const ll64*)&Bs[buf * 16384 + ru * 64 + slot * 16 + (lk & 1) * 8];
  };

  const int nk = K >> 6;    // 8
  STAGE(0, 0);
  STAGE(1, 1);
  for (int j = 0; j < nk; ++j) {
    const int bi = j & 3, bs = (j + 2) & 3;
    if (j == nk - 1) asm volatile("s_waitcnt vmcnt(0)" ::: "memory");
    else             asm volatile("s_waitcnt vmcnt(4)" ::: "memory");
    __builtin_amdgcn_s_barrier();
    __builtin_amdgcn_sched_barrier(0);
    ll64 aq[8][2], bq[4][2];
#pragma unroll
    for (int n = 0; n < 4; n++) { bq[n][0] = LDB8(bi, n, 0); bq[n][1] = LDB8(bi, n, 1); }
#pragma unroll
    for (int m = 0; m < 8; m++) { aq[m][0] = LDA8(bi, m, 0); aq[m][1] = LDA8(bi, m, 1); }
    if (j + 2 < nk) STAGE(j + 2, bs);
    asm volatile("s_waitcnt lgkmcnt(0)" ::: "memory");
    __builtin_amdgcn_sched_barrier(0);
    __builtin_amdgcn_s_setprio(1);
#pragma unroll
    for (int m = 0; m < 8; m++)
#pragma unroll
      for (int n = 0; n < 4; n++) {
        acc[m][n] = __builtin_amdgcn_mfma_f32_16x16x32_fp8_fp8(aq[m][0], bq[n][0], acc[m][n], 0, 0, 0);
        acc[m][n] = __builtin_amdgcn_mfma_f32_16x16x32_fp8_fp8(aq[m][1], bq[n][1], acc[m][n], 0, 0, 0);
      }
    __builtin_amdgcn_s_setprio(0);
    __builtin_amdgcn_sched_barrier(0);
  }

  // epilogue
  const int cl = la;
  const int rg = lk * 4;
  const int rowbase = brow + wr * 128;
  const int colbase = bcol + wc * 64;
  unsigned char* Cb = C + (size_t)bz * sC;
  const float* maskb = mask + (size_t)bz * 4096;
  float* partb = partial + ((size_t)bz * 64 + (size_t)(by * 4 + wc)) * M;
  const float sc2 = scale * 1.4426950408889634f;
  f32x4 rs[8];
#pragma unroll
  for (int m = 0; m < 8; m++) rs[m] = zero;
#pragma unroll
  for (int m = 0; m < 8; m++) {
#pragma unroll
    for (int n = 0; n < 4; n++) {
      const int col = colbase + n * 16 + cl;
      const float mk = maskb[col];
#pragma unroll
      for (int j = 0; j < 4; j++) {
        const int row = rowbase + m * 16 + rg + j;
        float v = mk * fast_exp2(acc[m][n][j] * sc2);
        rs[m][j] += v;
        Cb[(size_t)row * N + col] = f2fp8(v);
      }
    }
  }
#pragma unroll
  for (int off = 1; off < 16; off <<= 1)
#pragma unroll
    for (int m = 0; m < 8; m++) {
#pragma unroll
      for (int j = 0; j < 4; j++) rs[m][j] += __shfl_xor(rs[m][j], off);
    }
  if (cl == 0) {
#pragma unroll
    for (int m = 0; m < 8; m++) {
      float4 v = make_float4(rs[m][0], rs[m][1], rs[m][2], rs[m][3]);
      *(float4*)&partb[rowbase + m * 16 + rg] = v;
    }
  }
}

// ---------------- fp8 PV GEMM: BM=256, BN=128, BK=64 fp8, NBUF=4 circular ----------------
// 8 waves 2Mx4N (wave tile 128x32); epilogue acc*rinv[row] -> bf16 ot.
__global__ __launch_bounds__(512, 2)
void k_pv(const unsigned char* __restrict__ A, const unsigned char* __restrict__ B,
          unsigned short* __restrict__ C, const float* __restrict__ rinv,
          int M, int N, int K, int ldA, int ldB,
          size_t sA, size_t sB, size_t sC, int gx, int gy)
{
  __shared__ __align__(16) unsigned char As[4 * 16384];   // 64 KB
  __shared__ __align__(16) unsigned char Bs[4 * 8192];    // 32 KB

  const int lin = blockIdx.x;
  const int nwg = gridDim.x;
  const int wg = ((lin & 7) * (nwg >> 3)) + (lin >> 3);
  const int bx = wg % gx;
  const int t2 = wg / gx;
  const int by = t2 % gy;
  const int bz = t2 / gy;

  const unsigned char* Ab = A + (size_t)bz * sA;
  const unsigned char* Bb = B + (size_t)bz * sB;
  const int brow = bx * 256;
  const int bcol = by * 128;
  const int t = threadIdx.x;
  const int lane = t & 63;
  const int wid = t >> 6;
  const int wr = wid >> 2;
  const int wc = wid & 3;
  const int la = lane & 15;
  const int lk = lane >> 4;

  const f32x4 zero = {0.f, 0.f, 0.f, 0.f};
  f32x4 acc[8][2];
#pragma unroll
  for (int m = 0; m < 8; m++)
#pragma unroll
    for (int n = 0; n < 2; n++) acc[m][n] = zero;

  const unsigned char* srcA[2];
  const unsigned char* srcB1;
#pragma unroll
  for (int c = 0; c < 2; ++c) {
    const int q = c * 512 + t, r = q >> 2, s = (q & 3) ^ ((r >> 1) & 3);
    srcA[c] = Ab + (size_t)(brow + r) * ldA + s * 16;
  }
  {
    const int r = t >> 2, s = (t & 3) ^ ((r >> 1) & 3);
    srcB1 = Bb + (size_t)(bcol + r) * ldB + s * 16;
  }
  auto STAGE = [&](int kt, int buf) {
    const int ko = kt * 64;
#pragma unroll
    for (int c = 0; c < 2; ++c)
      gl_lds16b(srcA[c] + ko, &As[buf * 16384 + (c * 512 + t) * 16]);
    gl_lds16b(srcB1 + ko, &Bs[buf * 8192 + t * 16]);
  };
  auto LDA8 = [&](int buf, int m, int kst) -> ll64 {
    const int ru = wr * 128 + m * 16 + la;
    const int slot = ((kst << 1) | (lk >> 1)) ^ ((ru >> 1) & 3);
    return *(const ll64*)&As[buf * 16384 + ru * 64 + slot * 16 + (lk & 1) * 8];
  };
  auto LDB8 = [&](int buf, int n, int kst) -> ll64 {
    const int ru = wc * 32 + n * 16 + la;
    const int slot = ((kst << 1) | (lk >> 1)) ^ ((ru >> 1) & 3);
    return *(const ll64*)&Bs[buf * 8192 + ru * 64 + slot * 16 + (lk & 1) * 8];
  };

  const int nk = K >> 6;    // 64
  STAGE(0, 0);
  STAGE(1, 1);
  for (int j = 0; j < nk; ++j) {
    const int bi = j & 3, bs = (j + 2) & 3;
    if (j == nk - 1) asm volatile("s_waitcnt vmcnt(0)" ::: "memory");
    else             asm volatile("s_waitcnt vmcnt(3)" ::: "memory");
    __builtin_amdgcn_s_barrier();
    __builtin_amdgcn_sched_barrier(0);
    ll64 aq[8][2], bq[2][2];
#pragma unroll
    for (int n = 0; n < 2; n++) { bq[n][0] = LDB8(bi, n, 0); bq[n][1] = LDB8(bi, n, 1); }
#pragma unroll
    for (int m = 0; m < 8; m++) { aq[m][0] = LDA8(bi, m, 0); aq[m][1] = LDA8(bi, m, 1); }
    if (j + 2 < nk) STAGE(j + 2, bs);
    asm volatile("s_waitcnt lgkmcnt(0)" ::: "memory");
    __builtin_amdgcn_sched_barrier(0);
    __builtin_amdgcn_s_setprio(1);
#pragma unroll
    for (int m = 0; m < 8; m++)
#pragma unroll
      for (int n = 0; n < 2; n++) {
        acc[m][n] = __builtin_amdgcn_mfma_f32_16x16x32_fp8_fp8(aq[m][0], bq[n][0], acc[m][n], 0, 0, 0);
        acc[m][n] = __builtin_amdgcn_mfma_f32_16x16x32_fp8_fp8(aq[m][1], bq[n][1], acc[m][n], 0, 0, 0);
      }
    __builtin_amdgcn_s_setprio(0);
    __builtin_amdgcn_sched_barrier(0);
  }

  const int cl = la;
  const int rg = lk * 4;
  const int rowbase = brow + wr * 128;
  const int colbase = bcol + wc * 32;
  unsigned short* Cb = C + (size_t)bz * sC;
  const float* rb = rinv + (size_t)bz * 4096;
#pragma unroll
  for (int m = 0; m < 8; m++) {
    const float4 ri = *(const float4*)&rb[rowbase + m * 16 + rg];
    const float riv[4] = {ri.x, ri.y, ri.z, ri.w};
#pragma unroll
    for (int n = 0; n < 2; n++) {
      const int col = colbase + n * 16 + cl;
#pragma unroll
      for (int j = 0; j < 4; j++) {
        const int row = rowbase + m * 16 + rg + j;
        Cb[(size_t)row * N + col] = f2bf(acc[m][n][j] * riv[j]);
      }
    }
  }
}

// ---------------- rowsum reduce ----------------
__global__ __launch_bounds__(256) void rowsum_inv(const float* __restrict__ partial,
                                                  float* __restrict__ rinv){
  const int idx = blockIdx.x * 256 + threadIdx.x;
  const int b = idx >> 12, q = idx & 4095;
  const float* p = partial + ((size_t)b * 64) * 4096 + q;
  float s = 0.f;
#pragma unroll
  for (int i = 0; i < 64; i++) s += p[(size_t)i * 4096];
  rinv[idx] = 1.f / s;
}

extern "C" void kernel_launch(void* const* d_in, const int* in_sizes, int n_in,
                              void* d_out, int out_size, void* d_ws, size_t ws_size,
                              hipStream_t stream) {
  const float* x     = (const float*)d_in[0];
  const float* mask  = (const float*)d_in[1];
  const float* gamma = (const float*)d_in[2];
  const float* beta  = (const float*)d_in[3];
  const float* Wq    = (const float*)d_in[4];
  const float* bq    = (const float*)d_in[5];
  const float* Wk    = (const float*)d_in[6];
  const float* bk    = (const float*)d_in[7];
  const float* Wv    = (const float*)d_in[8];
  const float* bv    = (const float*)d_in[9];
  const float* Wo    = (const float*)d_in[10];
  const float* bo    = (const float*)d_in[11];
  float* out = (float*)d_out;

  size_t off = 0;
  auto nxt = [&](size_t bytes) -> void* {
    void* p = (char*)d_ws + off;
    off += (bytes + 255) & ~(size_t)255;
    return p;
  };
  float* stats          = (float*)nxt(256 * sizeof(float));
  float* spart          = (float*)nxt(2048 * sizeof(float));
  float* partial        = (float*)nxt((size_t)4 * 64 * 4096 * 4);
  float* rinv           = (float*)nxt((size_t)16384 * 4);
  unsigned short* Wqkb  = (unsigned short*)nxt((size_t)1024 * 512 * 2);
  unsigned short* Wvb   = (unsigned short*)nxt((size_t)512 * 512 * 2);
  unsigned short* Wob   = (unsigned short*)nxt((size_t)512 * 512 * 2);
  unsigned short* hnt   = (unsigned short*)nxt((size_t)16384 * 512 * 2);   // [b*4096+p][c] bf16
  unsigned char*  qk8   = (unsigned char*)nxt((size_t)2 * 16384 * 512);    // qt8 | kt8 fp8
  unsigned char*  vcm8  = (unsigned char*)nxt((size_t)4 * 512 * 4096);     // [b][c][p] fp8
  unsigned short* ot    = (unsigned short*)nxt((size_t)16384 * 512 * 2);   // bf16
  unsigned char*  P8    = (unsigned char*)nxt((size_t)4 * 4096 * 4096);    // fp8

  conv4<<<512, 256, 0, stream>>>(Wq, Wk, Wv, Wo, Wqkb, Wvb, Wob);

  gn_stats1<<<1024, 256, 0, stream>>>(x, spart);
  gn_stats2<<<1, 128, 0, stream>>>(spart, stats);
  gn_apply<<<dim3(128, 8, 4), 256, 0, stream>>>(x, stats, gamma, beta, hnt);

  // fused QK proj -> fp8 qt8/kt8 (separate contiguous buffers); gx=64, gy=8 -> 512
  k_qkproj<<<512, 512, 0, stream>>>(hnt, Wqkb, qk8, nullptr, bq, bk,
                                    16384, 1024, 512, 0, 0, 0, 64, 8);
  // V proj -> fp8 vcm8[b][c][p]; gx=2, gy=32, gz=4 -> 256
  k_vproj<<<256, 512, 0, stream>>>(Wvb, hnt, vcm8, nullptr, bv, nullptr,
                                   512, 4096, 512,
                                   0, (size_t)4096 * 512, (size_t)512 * 4096, 2, 32);
  // scores (fp8 in, fp8 P out + f32 partials); gx=16, gy=16, gz=4 -> 1024
  k_scores<<<1024, 512, 0, stream>>>(qk8, qk8 + (size_t)8388608, P8, mask, partial,
                                     4096, 4096, 512, 512, 512, 0.044194173824159216f,
                                     (size_t)4096 * 512, (size_t)4096 * 512,
                                     (size_t)4096 * 4096, 16, 16);
  rowsum_inv<<<64, 256, 0, stream>>>(partial, rinv);
  // PV (fp8 in, bf16 ot out, *rinv); gx=16, gy=4, gz=4 -> 256
  k_pv<<<256, 512, 0, stream>>>(P8, vcm8, ot, rinv,
                                4096, 512, 4096, 4096, 4096,
                                (size_t)4096 * 4096, (size_t)512 * 4096,
                                (size_t)4096 * 512, 16, 4);
  // O-projection + residual + bias -> fp32 out; gx=64, gy=4 -> 256
  k_oproj<<<256, 512, 0, stream>>>(ot, Wob, out, x, bo, 64, 4);
}

// Round 10
// 239.046 us; speedup vs baseline: 1.3266x; 1.0700x over previous
//
#include <hip/hip_runtime.h>
#include <hip/hip_bf16.h>
#include <stdint.h>

typedef __attribute__((ext_vector_type(4))) float f32x4;
typedef __attribute__((ext_vector_type(8))) __bf16 bf16x8;
typedef __attribute__((ext_vector_type(8))) unsigned short u16x8;
typedef long long ll64;
typedef __attribute__((ext_vector_type(2))) long long ll64x2;

__device__ __forceinline__ unsigned short f2bf(float f){
  uint32_t u = __builtin_bit_cast(uint32_t, f);
  u += 0x7FFFu + ((u >> 16) & 1u);
  return (unsigned short)(u >> 16);
}
__device__ __forceinline__ float bf2f(unsigned short h){
  return __builtin_bit_cast(float, ((uint32_t)h) << 16);
}
__device__ __forceinline__ float fast_exp2(float x){
#if __has_builtin(__builtin_amdgcn_exp2f)
  return __builtin_amdgcn_exp2f(x);
#else
  return exp2f(x);
#endif
}
__device__ __forceinline__ unsigned char f2fp8(float f){
#if __has_builtin(__builtin_amdgcn_cvt_pk_fp8_f32)
  int r = __builtin_amdgcn_cvt_pk_fp8_f32(f, f, 0, false);
  return (unsigned char)(r & 0xff);
#else
  uint32_t u = __builtin_bit_cast(uint32_t, f);
  uint32_t s = (u >> 24) & 0x80u;
  uint32_t a = u & 0x7fffffffu;
  float af = __builtin_bit_cast(float, a);
  if (af >= 448.f) return (unsigned char)(s | 0x7e);
  a += 0x000fffffu + ((a >> 20) & 1u);
  int e = (int)(a >> 23) - 127;
  if (e < -6) return (unsigned char)s;
  return (unsigned char)(s | (uint32_t)((e + 7) << 3) | ((a >> 20) & 7u));
#endif
}
// k-interleave permutation: lane lk's two 8B chunks (true k lk*8, 32+lk*8) contiguous
__device__ __forceinline__ int perm64(int c){
  return (c & ~63) | (((c >> 3) & 3) << 4) | (((c >> 5) & 1) << 3) | (c & 7);
}
__device__ __forceinline__ void gl_lds16(const unsigned short* g, unsigned short* l){
  __builtin_amdgcn_global_load_lds(
      (const __attribute__((address_space(1))) uint32_t*)g,
      (__attribute__((address_space(3))) uint32_t*)l, 16, 0, 0);
}
__device__ __forceinline__ void gl_lds16b(const unsigned char* g, unsigned char* l){
  __builtin_amdgcn_global_load_lds(
      (const __attribute__((address_space(1))) uint32_t*)g,
      (__attribute__((address_space(3))) uint32_t*)l, 16, 0, 0);
}

// ---------------- fp32 -> bf16 convert: Wq|Wk concat, Wv, Wo ----------------
__global__ __launch_bounds__(256) void conv4(const float* __restrict__ a, const float* __restrict__ b,
                                             const float* __restrict__ c, const float* __restrict__ d,
                                             unsigned short* __restrict__ oqk,
                                             unsigned short* __restrict__ ov,
                                             unsigned short* __restrict__ oo){
  const int bid = blockIdx.x;
  const int sel = bid >> 7;
  const float* in = sel == 0 ? a : sel == 1 ? b : sel == 2 ? c : d;
  unsigned short* out = sel == 0 ? oqk : sel == 1 ? (oqk + 262144) : sel == 2 ? ov : oo;
  const int i = ((bid & 127) * 256 + threadIdx.x) * 8;
  float4 v0 = *(const float4*)&in[i];
  float4 v1 = *(const float4*)&in[i + 4];
  u16x8 o;
  o[0]=f2bf(v0.x); o[1]=f2bf(v0.y); o[2]=f2bf(v0.z); o[3]=f2bf(v0.w);
  o[4]=f2bf(v1.x); o[5]=f2bf(v1.y); o[6]=f2bf(v1.z); o[7]=f2bf(v1.w);
  *(u16x8*)&out[i] = o;
}

// ---------------- GroupNorm stats, 2-stage ----------------
__global__ __launch_bounds__(256) void gn_stats1(const float* __restrict__ x,
                                                 float* __restrict__ part){
  const int bid = blockIdx.x;
  const float* p = x + (size_t)bid * 8192;
  float s = 0.f, ss = 0.f;
  for (int i = threadIdx.x; i < 2048; i += 256) {
    float4 v = *(const float4*)(p + (size_t)i * 4);
    s  += v.x + v.y + v.z + v.w;
    ss += v.x*v.x + v.y*v.y + v.z*v.z + v.w*v.w;
  }
  for (int off = 32; off; off >>= 1) { s += __shfl_down(s, off); ss += __shfl_down(ss, off); }
  __shared__ float red[8];
  int w = threadIdx.x >> 6;
  if ((threadIdx.x & 63) == 0) { red[w] = s; red[w + 4] = ss; }
  __syncthreads();
  if (threadIdx.x == 0) {
    part[bid * 2]     = red[0] + red[1] + red[2] + red[3];
    part[bid * 2 + 1] = red[4] + red[5] + red[6] + red[7];
  }
}
__global__ __launch_bounds__(128) void gn_stats2(const float* __restrict__ part,
                                                 float* __restrict__ stats){
  const int g = threadIdx.x;
  float s = 0.f, ss = 0.f;
#pragma unroll
  for (int i = 0; i < 8; i++) { s += part[(g * 8 + i) * 2]; ss += part[(g * 8 + i) * 2 + 1]; }
  float mean = s * (1.f / 65536.f);
  float var  = ss * (1.f / 65536.f) - mean * mean;
  stats[g * 2]     = mean;
  stats[g * 2 + 1] = rsqrtf(var + 1e-6f);
}

// ---------------- GN apply + transpose ----------------
__global__ __launch_bounds__(256) void gn_apply(const float* __restrict__ x,
                                                const float* __restrict__ stats,
                                                const float* __restrict__ gamma,
                                                const float* __restrict__ beta,
                                                unsigned short* __restrict__ hn_t){
  __shared__ float tile[64][33];
  const int b  = blockIdx.z;
  const int c0 = blockIdx.y * 64;
  const int p0 = blockIdx.x * 32;
  const int t  = threadIdx.x;
  const float* xb = x + (size_t)b * 512 * 4096;
  const int lpx = t & 31, lcc = t >> 5;
#pragma unroll
  for (int i = 0; i < 8; i++)
    tile[lcc + i * 8][lpx] = xb[(size_t)(c0 + lcc + i * 8) * 4096 + p0 + lpx];
  __syncthreads();
  unsigned short* hb = hn_t + (size_t)b * 4096 * 512;
  const int c   = c0 + (t & 31) * 2;
  const int pxi = t >> 5;
  const int g2  = (b * 32 + (c >> 4)) * 2;
  const float mean = stats[g2], rstd = stats[g2 + 1];
  const float ga0 = gamma[c], be0 = beta[c];
  const float ga1 = gamma[c + 1], be1 = beta[c + 1];
#pragma unroll
  for (int i = 0; i < 4; i++) {
    const int px = pxi + i * 8;
    float v0 = tile[(t & 31) * 2][px];
    float v1 = tile[(t & 31) * 2 + 1][px];
    uint32_t h0 = f2bf((v0 - mean) * rstd * ga0 + be0);
    uint32_t h1 = f2bf((v1 - mean) * rstd * ga1 + be1);
    *(uint32_t*)&hb[(size_t)(p0 + px) * 512 + c] = h0 | (h1 << 16);
  }
}

// ---------------- R5-structure bf16 GEMM (projections): BM=256, BN=128, BK=64 ----------------
// MODE 1: +bias(qk split) -> FP8 to qt8/kt8 (k-interleaved cols)
// MODE 2: +bias[row] -> FP8 to vcm8 (k-interleaved cols)
// MODE 5: acc+resid+bias[col] -> fp32 transposed out
template<int MODE>
__device__ __forceinline__ void gemm_body5(
    const unsigned short* __restrict__ A, const unsigned short* __restrict__ B,
    unsigned char* __restrict__ C8, float* __restrict__ OUTF,
    const float* __restrict__ auxA, const float* __restrict__ auxB,
    int M, int N, int K, size_t sA, size_t sB, size_t sC, int gx, int gy)
{
  constexpr int NF = 2;
  __shared__ __align__(16) unsigned short As[4 * 8192];
  __shared__ __align__(16) unsigned short Bs[2 * 8192];

  const int lin = blockIdx.x;
  const int nwg = gridDim.x;
  const int wg = ((lin & 7) * (nwg >> 3)) + (lin >> 3);
  const int bx = wg % gx;
  const int t2 = wg / gx;
  const int by = t2 % gy;
  const int bz = t2 / gy;

  const unsigned short* Ab = A + (size_t)bz * sA;
  const unsigned short* Bb = B + (size_t)bz * sB;
  const int brow = bx * 256;
  const int bcol = by * 128;
  const int t = threadIdx.x;
  const int lane = t & 63;
  const int wid = t >> 6;
  const int wr = wid >> 2;
  const int wc = wid & 3;
  const int la = lane & 15;
  const int lk = lane >> 4;
  const int axr = la >> 1;

  const f32x4 zero = {0.f, 0.f, 0.f, 0.f};
  f32x4 acc[8][NF];
#pragma unroll
  for (int m = 0; m < 8; m++)
#pragma unroll
    for (int n = 0; n < NF; n++) acc[m][n] = zero;

  const int ru0 = t >> 3, s0 = t & 7;
  const int gx0 = s0 ^ ((ru0 >> 1) & 7);

  auto stageA = [&](int kt, int h) {
    unsigned short* base = As + ((kt & 1) * 2 + h) * 8192;
    const size_t ko = (size_t)kt * 64;
    gl_lds16(Ab + (size_t)(brow + h * 64 + ru0) * K + ko + gx0 * 8, base + t * 8);
    gl_lds16(Ab + (size_t)(brow + 128 + h * 64 + ru0) * K + ko + gx0 * 8, base + 4096 + t * 8);
  };
  auto stageBf = [&](int kt) {
    unsigned short* base = Bs + (kt & 1) * 8192;
    const size_t ko = (size_t)kt * 64;
    gl_lds16(Bb + (size_t)(bcol + ru0) * K + ko + gx0 * 8, base + t * 8);
    gl_lds16(Bb + (size_t)(bcol + 64 + ru0) * K + ko + gx0 * 8, base + 4096 + t * 8);
  };
  auto LDA = [&](int db, int mh, int i, int kst) -> bf16x8 {
    const int ru = wr * 64 + i * 16 + la;
    const int slot = ((kst << 2) | lk) ^ axr;
    return __builtin_bit_cast(bf16x8, *(const u16x8*)&As[(db * 2 + mh) * 8192 + ru * 64 + slot * 8]);
  };
  auto LDB = [&](int db, int n2, int kst) -> bf16x8 {
    const int ru = wc * 32 + n2 * 16 + la;
    const int slot = ((kst << 2) | lk) ^ axr;
    return __builtin_bit_cast(bf16x8, *(const u16x8*)&Bs[db * 8192 + ru * 64 + slot * 8]);
  };

#define DSR5(mh) \
  bf16x8 aq[4][2], bq[2][2]; \
  _Pragma("unroll") for (int i = 0; i < 4; ++i) { aq[i][0] = LDA(db, mh, i, 0); aq[i][1] = LDA(db, mh, i, 1); } \
  _Pragma("unroll") for (int n2 = 0; n2 < 2; ++n2) { bq[n2][0] = LDB(db, n2, 0); bq[n2][1] = LDB(db, n2, 1); }

#define MM5(mh) \
  asm volatile("s_waitcnt lgkmcnt(0)" ::: "memory"); \
  __builtin_amdgcn_sched_barrier(0); \
  __builtin_amdgcn_s_setprio(1); \
  _Pragma("unroll") for (int i = 0; i < 4; ++i) \
    _Pragma("unroll") for (int n2 = 0; n2 < 2; ++n2) { \
      acc[(mh)*4+i][n2] = __builtin_amdgcn_mfma_f32_16x16x32_bf16(aq[i][0], bq[n2][0], acc[(mh)*4+i][n2], 0, 0, 0); \
      acc[(mh)*4+i][n2] = __builtin_amdgcn_mfma_f32_16x16x32_bf16(aq[i][1], bq[n2][1], acc[(mh)*4+i][n2], 0, 0, 0); } \
  __builtin_amdgcn_s_setprio(0); \
  __builtin_amdgcn_sched_barrier(0);

#define PHASE5(VMS, mh, STG) do { \
  asm volatile("s_waitcnt vmcnt(" VMS ")" ::: "memory"); \
  __builtin_amdgcn_s_barrier(); \
  DSR5(mh); \
  STG; \
  MM5(mh); \
} while (0)

  const int nk = K >> 6;
  stageA(0, 0); stageBf(0); stageA(0, 1);
  for (int j = 0; j < nk - 1; ++j) {
    const int db = j & 1;
    PHASE5("2", 0, { stageA(j + 1, 0); stageBf(j + 1); });
    PHASE5("4", 1, { stageA(j + 1, 1); });
  }
  {
    const int db = (nk - 1) & 1;
    asm volatile("s_waitcnt vmcnt(0)" ::: "memory");
    __builtin_amdgcn_s_barrier();
    { DSR5(0); MM5(0); }
    { DSR5(1); MM5(1); }
  }
#undef PHASE5
#undef MM5
#undef DSR5

  const int cl = la;
  const int rg = lk * 4;
  const int rowbase = brow + wr * 128;
  const int colbase = bcol + wc * 32;

  if (MODE == 1) {
    // C8: qt8 (16384x512) then kt8 at +8388608; store k-interleaved
#pragma unroll
    for (int m = 0; m < 8; m++) {
#pragma unroll
      for (int n = 0; n < NF; n++) {
        const int col = colbase + n * 16 + cl;
        const float bcv = (col < 512 ? auxA[col] : auxB[col - 512]);
        unsigned char* dst = C8 + (col < 512 ? 0 : (size_t)8388608);
        const int c9 = perm64(col & 511);
#pragma unroll
        for (int j = 0; j < 4; j++) {
          const int row = rowbase + m * 16 + rg + j;
          dst[(size_t)row * 512 + c9] = f2fp8(acc[m][n][j] + bcv);
        }
      }
    }
  } else if (MODE == 2) {
    unsigned char* Cb = C8 + (size_t)bz * sC;
#pragma unroll
    for (int m = 0; m < 8; m++) {
#pragma unroll
      for (int n = 0; n < NF; n++) {
        const int col = colbase + n * 16 + cl;
        const int cp = perm64(col);
#pragma unroll
        for (int j = 0; j < 4; j++) {
          const int row = rowbase + m * 16 + rg + j;
          Cb[(size_t)row * N + cp] = f2fp8(acc[m][n][j] + auxA[row]);
        }
      }
    }
  } else { // MODE 5
#pragma unroll
    for (int m = 0; m < 8; m++) {
      const int row = rowbase + m * 16 + rg;
      const int bb = row >> 12;
      const int p  = row & 4095;
#pragma unroll
      for (int n = 0; n < NF; n++) {
        const int col = colbase + n * 16 + cl;
        const size_t idx = ((size_t)bb * 512 + col) * 4096 + p;
        const float4 xv = *(const float4*)&auxA[idx];
        const float bv = auxB[col];
        float4 ov;
        ov.x = acc[m][n][0] + xv.x + bv;
        ov.y = acc[m][n][1] + xv.y + bv;
        ov.z = acc[m][n][2] + xv.z + bv;
        ov.w = acc[m][n][3] + xv.w + bv;
        *(float4*)&OUTF[idx] = ov;
      }
    }
  }
}

#define GEMM_ARGS const unsigned short* A, const unsigned short* B, unsigned char* C8, \
                  float* OUTF, const float* auxA, const float* auxB, \
                  int M, int N, int K, size_t sA, size_t sB, size_t sC, int gx, int gy
#define GEMM_PASS A, B, C8, OUTF, auxA, auxB, M, N, K, sA, sB, sC, gx, gy

__global__ __launch_bounds__(512, 2) void k_qkproj(GEMM_ARGS){ gemm_body5<1>(GEMM_PASS); }
__global__ __launch_bounds__(512, 2) void k_vproj (GEMM_ARGS){ gemm_body5<2>(GEMM_PASS); }

__global__ __launch_bounds__(512, 2) void k_oproj(const unsigned short* A, const unsigned short* B,
                                                  float* OUTF, const float* resid, const float* bias,
                                                  int gx, int gy){
  gemm_body5<5>(A, B, nullptr, OUTF, resid, bias, 16384, 512, 512, 0, 0, 0, gx, gy);
}

// ---------------- fp8 scores GEMM: BM=BN=256, BK=64 fp8 (k-interleaved), NBUF=4 ----------------
// Lane reads ONE ds_read_b128 per fragment pair (both 8B k-chunks contiguous).
__global__ __launch_bounds__(512, 2)
void k_scores(const unsigned char* __restrict__ A, const unsigned char* __restrict__ B,
              unsigned char* __restrict__ C, const float* __restrict__ mask,
              float* __restrict__ partial,
              int M, int N, int K, int ldA, int ldB, float scale,
              size_t sA, size_t sB, size_t sC, int gx, int gy)
{
  __shared__ __align__(16) unsigned char As[4 * 16384];
  __shared__ __align__(16) unsigned char Bs[4 * 16384];

  const int lin = blockIdx.x;
  const int nwg = gridDim.x;
  const int wg = ((lin & 7) * (nwg >> 3)) + (lin >> 3);
  const int bx = wg % gx;
  const int t2 = wg / gx;
  const int by = t2 % gy;
  const int bz = t2 / gy;

  const unsigned char* Ab = A + (size_t)bz * sA;
  const unsigned char* Bb = B + (size_t)bz * sB;
  const int brow = bx * 256;
  const int bcol = by * 256;
  const int t = threadIdx.x;
  const int lane = t & 63;
  const int wid = t >> 6;
  const int wr = wid >> 2;
  const int wc = wid & 3;
  const int la = lane & 15;
  const int lk = lane >> 4;

  const f32x4 zero = {0.f, 0.f, 0.f, 0.f};
  f32x4 acc[8][4];
#pragma unroll
  for (int m = 0; m < 8; m++)
#pragma unroll
    for (int n = 0; n < 4; n++) acc[m][n] = zero;

  const unsigned char* srcA[2];
  const unsigned char* srcB[2];
#pragma unroll
  for (int c = 0; c < 2; ++c) {
    const int q = c * 512 + t, r = q >> 2, s = (q & 3) ^ ((r >> 1) & 3);
    srcA[c] = Ab + (size_t)(brow + r) * ldA + s * 16;
    srcB[c] = Bb + (size_t)(bcol + r) * ldB + s * 16;
  }
  auto STAGE = [&](int kt, int buf) {
    const int ko = kt * 64;
#pragma unroll
    for (int c = 0; c < 2; ++c) {
      gl_lds16b(srcA[c] + ko, &As[buf * 16384 + (c * 512 + t) * 16]);
      gl_lds16b(srcB[c] + ko, &Bs[buf * 16384 + (c * 512 + t) * 16]);
    }
  };
  auto LDA8 = [&](int buf, int m) -> ll64x2 {
    const int ru = wr * 128 + m * 16 + la;
    const int slot = lk ^ ((ru >> 1) & 3);
    return *(const ll64x2*)&As[buf * 16384 + ru * 64 + slot * 16];
  };
  auto LDB8 = [&](int buf, int n) -> ll64x2 {
    const int ru = wc * 64 + n * 16 + la;
    const int slot = lk ^ ((ru >> 1) & 3);
    return *(const ll64x2*)&Bs[buf * 16384 + ru * 64 + slot * 16];
  };

  const int nk = K >> 6;    // 8
  STAGE(0, 0);
  STAGE(1, 1);
  for (int j = 0; j < nk; ++j) {
    const int bi = j & 3, bs = (j + 2) & 3;
    if (j == nk - 1) asm volatile("s_waitcnt vmcnt(0)" ::: "memory");
    else             asm volatile("s_waitcnt vmcnt(4)" ::: "memory");
    __builtin_amdgcn_s_barrier();
    __builtin_amdgcn_sched_barrier(0);
    ll64x2 aq[8], bq[4];
#pragma unroll
    for (int n = 0; n < 4; n++) bq[n] = LDB8(bi, n);
#pragma unroll
    for (int m = 0; m < 8; m++) aq[m] = LDA8(bi, m);
    if (j + 2 < nk) STAGE(j + 2, bs);
    asm volatile("s_waitcnt lgkmcnt(0)" ::: "memory");
    __builtin_amdgcn_sched_barrier(0);
    __builtin_amdgcn_s_setprio(1);
#pragma unroll
    for (int m = 0; m < 8; m++)
#pragma unroll
      for (int n = 0; n < 4; n++) {
        acc[m][n] = __builtin_amdgcn_mfma_f32_16x16x32_fp8_fp8(aq[m][0], bq[n][0], acc[m][n], 0, 0, 0);
        acc[m][n] = __builtin_amdgcn_mfma_f32_16x16x32_fp8_fp8(aq[m][1], bq[n][1], acc[m][n], 0, 0, 0);
      }
    __builtin_amdgcn_s_setprio(0);
    __builtin_amdgcn_sched_barrier(0);
  }

  // epilogue
  const int cl = la;
  const int rg = lk * 4;
  const int rowbase = brow + wr * 128;
  const int colbase = bcol + wc * 64;
  unsigned char* Cb = C + (size_t)bz * sC;
  const float* maskb = mask + (size_t)bz * 4096;
  float* partb = partial + ((size_t)bz * 64 + (size_t)(by * 4 + wc)) * M;
  const float sc2 = scale * 1.4426950408889634f;
  f32x4 rs[8];
#pragma unroll
  for (int m = 0; m < 8; m++) rs[m] = zero;
#pragma unroll
  for (int m = 0; m < 8; m++) {
#pragma unroll
    for (int n = 0; n < 4; n++) {
      const int col = colbase + n * 16 + cl;
      const float mk = maskb[col];
      const int cp = perm64(col);
#pragma unroll
      for (int j = 0; j < 4; j++) {
        const int row = rowbase + m * 16 + rg + j;
        float v = mk * fast_exp2(acc[m][n][j] * sc2);
        rs[m][j] += v;
        Cb[(size_t)row * N + cp] = f2fp8(v);
      }
    }
  }
#pragma unroll
  for (int off = 1; off < 16; off <<= 1)
#pragma unroll
    for (int m = 0; m < 8; m++) {
#pragma unroll
      for (int j = 0; j < 4; j++) rs[m][j] += __shfl_xor(rs[m][j], off);
    }
  if (cl == 0) {
#pragma unroll
    for (int m = 0; m < 8; m++) {
      float4 v = make_float4(rs[m][0], rs[m][1], rs[m][2], rs[m][3]);
      *(float4*)&partb[rowbase + m * 16 + rg] = v;
    }
  }
}

// ---------------- fp8 PV GEMM: BM=256, BN=128, BK=64 fp8 (k-interleaved), NBUF=4 ----------------
__global__ __launch_bounds__(512, 2)
void k_pv(const unsigned char* __restrict__ A, const unsigned char* __restrict__ B,
          unsigned short* __restrict__ C, const float* __restrict__ rinv,
          int M, int N, int K, int ldA, int ldB,
          size_t sA, size_t sB, size_t sC, int gx, int gy)
{
  __shared__ __align__(16) unsigned char As[4 * 16384];
  __shared__ __align__(16) unsigned char Bs[4 * 8192];

  const int lin = blockIdx.x;
  const int nwg = gridDim.x;
  const int wg = ((lin & 7) * (nwg >> 3)) + (lin >> 3);
  const int bx = wg % gx;
  const int t2 = wg / gx;
  const int by = t2 % gy;
  const int bz = t2 / gy;

  const unsigned char* Ab = A + (size_t)bz * sA;
  const unsigned char* Bb = B + (size_t)bz * sB;
  const int brow = bx * 256;
  const int bcol = by * 128;
  const int t = threadIdx.x;
  const int lane = t & 63;
  const int wid = t >> 6;
  const int wr = wid >> 2;
  const int wc = wid & 3;
  const int la = lane & 15;
  const int lk = lane >> 4;

  const f32x4 zero = {0.f, 0.f, 0.f, 0.f};
  f32x4 acc[8][2];
#pragma unroll
  for (int m = 0; m < 8; m++)
#pragma unroll
    for (int n = 0; n < 2; n++) acc[m][n] = zero;

  const unsigned char* srcA[2];
  const unsigned char* srcB1;
#pragma unroll
  for (int c = 0; c < 2; ++c) {
    const int q = c * 512 + t, r = q >> 2, s = (q & 3) ^ ((r >> 1) & 3);
    srcA[c] = Ab + (size_t)(brow + r) * ldA + s * 16;
  }
  {
    const int r = t >> 2, s = (t & 3) ^ ((r >> 1) & 3);
    srcB1 = Bb + (size_t)(bcol + r) * ldB + s * 16;
  }
  auto STAGE = [&](int kt, int buf) {
    const int ko = kt * 64;
#pragma unroll
    for (int c = 0; c < 2; ++c)
      gl_lds16b(srcA[c] + ko, &As[buf * 16384 + (c * 512 + t) * 16]);
    gl_lds16b(srcB1 + ko, &Bs[buf * 8192 + t * 16]);
  };
  auto LDA8 = [&](int buf, int m) -> ll64x2 {
    const int ru = wr * 128 + m * 16 + la;
    const int slot = lk ^ ((ru >> 1) & 3);
    return *(const ll64x2*)&As[buf * 16384 + ru * 64 + slot * 16];
  };
  auto LDB8 = [&](int buf, int n) -> ll64x2 {
    const int ru = wc * 32 + n * 16 + la;
    const int slot = lk ^ ((ru >> 1) & 3);
    return *(const ll64x2*)&Bs[buf * 8192 + ru * 64 + slot * 16];
  };

  const int nk = K >> 6;    // 64
  STAGE(0, 0);
  STAGE(1, 1);
  for (int j = 0; j < nk; ++j) {
    const int bi = j & 3, bs = (j + 2) & 3;
    if (j == nk - 1) asm volatile("s_waitcnt vmcnt(0)" ::: "memory");
    else             asm volatile("s_waitcnt vmcnt(3)" ::: "memory");
    __builtin_amdgcn_s_barrier();
    __builtin_amdgcn_sched_barrier(0);
    ll64x2 aq[8], bq[2];
#pragma unroll
    for (int n = 0; n < 2; n++) bq[n] = LDB8(bi, n);
#pragma unroll
    for (int m = 0; m < 8; m++) aq[m] = LDA8(bi, m);
    if (j + 2 < nk) STAGE(j + 2, bs);
    asm volatile("s_waitcnt lgkmcnt(0)" ::: "memory");
    __builtin_amdgcn_sched_barrier(0);
    __builtin_amdgcn_s_setprio(1);
#pragma unroll
    for (int m = 0; m < 8; m++)
#pragma unroll
      for (int n = 0; n < 2; n++) {
        acc[m][n] = __builtin_amdgcn_mfma_f32_16x16x32_fp8_fp8(aq[m][0], bq[n][0], acc[m][n], 0, 0, 0);
        acc[m][n] = __builtin_amdgcn_mfma_f32_16x16x32_fp8_fp8(aq[m][1], bq[n][1], acc[m][n], 0, 0, 0);
      }
    __builtin_amdgcn_s_setprio(0);
    __builtin_amdgcn_sched_barrier(0);
  }

  const int cl = la;
  const int rg = lk * 4;
  const int rowbase = brow + wr * 128;
  const int colbase = bcol + wc * 32;
  unsigned short* Cb = C + (size_t)bz * sC;
  const float* rb = rinv + (size_t)bz * 4096;
#pragma unroll
  for (int m = 0; m < 8; m++) {
    const float4 ri = *(const float4*)&rb[rowbase + m * 16 + rg];
    const float riv[4] = {ri.x, ri.y, ri.z, ri.w};
#pragma unroll
    for (int n = 0; n < 2; n++) {
      const int col = colbase + n * 16 + cl;
#pragma unroll
      for (int j = 0; j < 4; j++) {
        const int row = rowbase + m * 16 + rg + j;
        Cb[(size_t)row * N + col] = f2bf(acc[m][n][j] * riv[j]);
      }
    }
  }
}

// ---------------- rowsum reduce ----------------
__global__ __launch_bounds__(256) void rowsum_inv(const float* __restrict__ partial,
                                                  float* __restrict__ rinv){
  const int idx = blockIdx.x * 256 + threadIdx.x;
  const int b = idx >> 12, q = idx & 4095;
  const float* p = partial + ((size_t)b * 64) * 4096 + q;
  float s = 0.f;
#pragma unroll
  for (int i = 0; i < 64; i++) s += p[(size_t)i * 4096];
  rinv[idx] = 1.f / s;
}

extern "C" void kernel_launch(void* const* d_in, const int* in_sizes, int n_in,
                              void* d_out, int out_size, void* d_ws, size_t ws_size,
                              hipStream_t stream) {
  const float* x     = (const float*)d_in[0];
  const float* mask  = (const float*)d_in[1];
  const float* gamma = (const float*)d_in[2];
  const float* beta  = (const float*)d_in[3];
  const float* Wq    = (const float*)d_in[4];
  const float* bq    = (const float*)d_in[5];
  const float* Wk    = (const float*)d_in[6];
  const float* bk    = (const float*)d_in[7];
  const float* Wv    = (const float*)d_in[8];
  const float* bv    = (const float*)d_in[9];
  const float* Wo    = (const float*)d_in[10];
  const float* bo    = (const float*)d_in[11];
  float* out = (float*)d_out;

  size_t off = 0;
  auto nxt = [&](size_t bytes) -> void* {
    void* p = (char*)d_ws + off;
    off += (bytes + 255) & ~(size_t)255;
    return p;
  };
  float* stats          = (float*)nxt(256 * sizeof(float));
  float* spart          = (float*)nxt(2048 * sizeof(float));
  float* partial        = (float*)nxt((size_t)4 * 64 * 4096 * 4);
  float* rinv           = (float*)nxt((size_t)16384 * 4);
  unsigned short* Wqkb  = (unsigned short*)nxt((size_t)1024 * 512 * 2);
  unsigned short* Wvb   = (unsigned short*)nxt((size_t)512 * 512 * 2);
  unsigned short* Wob   = (unsigned short*)nxt((size_t)512 * 512 * 2);
  unsigned short* hnt   = (unsigned short*)nxt((size_t)16384 * 512 * 2);   // [b*4096+p][c] bf16
  unsigned char*  qk8   = (unsigned char*)nxt((size_t)2 * 16384 * 512);    // qt8 | kt8 fp8 k-ilv
  unsigned char*  vcm8  = (unsigned char*)nxt((size_t)4 * 512 * 4096);     // [b][c][p] fp8 k-ilv
  unsigned short* ot    = (unsigned short*)nxt((size_t)16384 * 512 * 2);   // bf16
  unsigned char*  P8    = (unsigned char*)nxt((size_t)4 * 4096 * 4096);    // fp8 k-ilv cols

  conv4<<<512, 256, 0, stream>>>(Wq, Wk, Wv, Wo, Wqkb, Wvb, Wob);

  gn_stats1<<<1024, 256, 0, stream>>>(x, spart);
  gn_stats2<<<1, 128, 0, stream>>>(spart, stats);
  gn_apply<<<dim3(128, 8, 4), 256, 0, stream>>>(x, stats, gamma, beta, hnt);

  // fused QK proj -> fp8 qt8/kt8 (k-interleaved); gx=64, gy=8 -> 512
  k_qkproj<<<512, 512, 0, stream>>>(hnt, Wqkb, qk8, nullptr, bq, bk,
                                    16384, 1024, 512, 0, 0, 0, 64, 8);
  // V proj -> fp8 vcm8[b][c][p] (p k-interleaved); gx=2, gy=32, gz=4 -> 256
  k_vproj<<<256, 512, 0, stream>>>(Wvb, hnt, vcm8, nullptr, bv, nullptr,
                                   512, 4096, 512,
                                   0, (size_t)4096 * 512, (size_t)512 * 4096, 2, 32);
  // scores (fp8 in, fp8 P out + f32 partials); gx=16, gy=16, gz=4 -> 1024
  k_scores<<<1024, 512, 0, stream>>>(qk8, qk8 + (size_t)8388608, P8, mask, partial,
                                     4096, 4096, 512, 512, 512, 0.044194173824159216f,
                                     (size_t)4096 * 512, (size_t)4096 * 512,
                                     (size_t)4096 * 4096, 16, 16);
  rowsum_inv<<<64, 256, 0, stream>>>(partial, rinv);
  // PV (fp8 in, bf16 ot out, *rinv); gx=16, gy=4, gz=4 -> 256
  k_pv<<<256, 512, 0, stream>>>(P8, vcm8, ot, rinv,
                                4096, 512, 4096, 4096, 4096,
                                (size_t)4096 * 4096, (size_t)512 * 4096,
                                (size_t)4096 * 512, 16, 4);
  // O-projection + residual + bias -> fp32 out; gx=64, gy=4 -> 256
  k_oproj<<<256, 512, 0, stream>>>(ot, Wob, out, x, bo, 64, 4);
}